// Round 3
// baseline (4479.952 us; speedup 1.0000x reference)
//
#include <hip/hip_runtime.h>
#include <hip/hip_bf16.h>

#define N_NODES 50000
#define N_EDGES 800000
#define DIM 128
#define N_GR 500
#define N_OUT 10

typedef unsigned short u16;
typedef unsigned int u32;

__device__ __forceinline__ float bf2f(u16 u) {
    union { u32 i; float f; } c; c.i = ((u32)u) << 16; return c.f;
}
__device__ __forceinline__ u16 f2bf(float f) {
    union { float f; u32 i; } c; c.f = f;
    u32 i = c.i;
    u32 r = i + 0x7FFFu + ((i >> 16) & 1u);
    return (u16)(r >> 16);
}

// ---------------- gather: x = emb[x_ids], f32 copy into d_out ----------------
__global__ __launch_bounds__(256) void k_gather(const int* __restrict__ ids,
                                                const float* __restrict__ emb,
                                                float* __restrict__ xout) {
    int gid = blockIdx.x * 256 + threadIdx.x;          // N*32 threads
    if (gid >= N_NODES * 32) return;
    int node = gid >> 5, seg = gid & 31;
    int id = ids[node];
    float4 v = *(const float4*)(emb + id * DIM + seg * 4);
    *(float4*)(xout + node * DIM + seg * 4) = v;
}

// ------------- scatter-add (f32 input): agg[dst] += x[src] -------------------
__global__ __launch_bounds__(256) void k_scatter_f32(const float* __restrict__ x,
                                                     const int* __restrict__ src,
                                                     const int* __restrict__ dst,
                                                     float* __restrict__ agg) {
    int gid = blockIdx.x * 256 + threadIdx.x;          // E*32 threads
    if (gid >= N_EDGES * 32) return;
    int e = gid >> 5, seg = gid & 31;
    int s = src[e], d = dst[e];
    float4 v = *(const float4*)(x + s * DIM + seg * 4);
    float* a = agg + d * DIM + seg * 4;
    unsafeAtomicAdd(a + 0, v.x); unsafeAtomicAdd(a + 1, v.y);
    unsafeAtomicAdd(a + 2, v.z); unsafeAtomicAdd(a + 3, v.w);
}

// ------------- scatter-add (bf16 input): agg[dst] += h[src] ------------------
__global__ __launch_bounds__(256) void k_scatter_bf16(const u16* __restrict__ x,
                                                      const int* __restrict__ src,
                                                      const int* __restrict__ dst,
                                                      float* __restrict__ agg) {
    int gid = blockIdx.x * 256 + threadIdx.x;          // E*16 threads
    if (gid >= N_EDGES * 16) return;
    int e = gid >> 4, seg = gid & 15;
    int s = src[e], d = dst[e];
    uint4 v = *(const uint4*)(x + s * DIM + seg * 8);
    float* a = agg + d * DIM + seg * 8;
    const u16* pv = (const u16*)&v;
#pragma unroll
    for (int j = 0; j < 8; j++) unsafeAtomicAdd(a + j, bf2f(pv[j]));
}

// ------- fused GIN MLP: h = relu( relu(bn((x+agg)@wa+ba)) @ wb + bb ) ---------
// weights f32 in HBM -> bf16 in LDS (32K), + vbuf 8K + mid 8K + 2K = 51.2K LDS
template<bool BF16IN>
__global__ __launch_bounds__(256) void k_mlp(const void* __restrict__ xin_,
                                             const float* __restrict__ agg,
                                             const float* __restrict__ wa, const float* __restrict__ ba,
                                             const float* __restrict__ gg, const float* __restrict__ be,
                                             const float* __restrict__ mm, const float* __restrict__ vv,
                                             const float* __restrict__ wb, const float* __restrict__ bb,
                                             u16* __restrict__ hout, int n) {
    __shared__ u16 w_s[DIM * DIM];                     // 32 KB (wa, then wb)
    __shared__ float sc_s[DIM], sh_s[DIM], ba_s[DIM], bb_s[DIM];
    __shared__ float vbuf[16][DIM];                    // 8 KB
    __shared__ float mid[16][DIM];                     // 8 KB
    int tid = threadIdx.x;

    {   // stage wa into LDS as packed bf16 pairs
        u32* d0 = (u32*)w_s;
        const float2* s0 = (const float2*)wa;
        for (int i = tid; i < DIM * DIM / 2; i += 256) {
            float2 p = s0[i];
            d0[i] = (u32)f2bf(p.x) | ((u32)f2bf(p.y) << 16);
        }
    }
    if (tid < DIM) {
        float s = gg[tid] * rsqrtf(vv[tid] + 1e-5f);
        sc_s[tid] = s;
        sh_s[tid] = be[tid] - mm[tid] * s;
        ba_s[tid] = ba[tid];
        bb_s[tid] = bb[tid];
    }
    int base = blockIdx.x * 16;
    for (int i = tid; i < 16 * DIM; i += 256) {
        int nn = i >> 7, k = i & 127;
        int node = base + nn;
        float val = 0.f;
        if (node < n) {
            float xv = BF16IN ? bf2f(((const u16*)xin_)[node * DIM + k])
                              : ((const float*)xin_)[node * DIM + k];
            val = xv + agg[node * DIM + k];
        }
        vbuf[nn][k] = val;
    }
    __syncthreads();

    int j0 = (tid & 63) * 2;
    // phase 1: Linear1 + BN + ReLU -> mid (wave w handles rows w,4+w,8+w,12+w)
#pragma unroll
    for (int rep = 0; rep < 4; rep++) {
        int nn = rep * 4 + (tid >> 6);
        float a0 = ba_s[j0], a1 = ba_s[j0 + 1];
#pragma unroll 8
        for (int k = 0; k < DIM; k++) {
            u32 w = *(const u32*)(w_s + k * DIM + j0);
            float vk = vbuf[nn][k];
            a0 = fmaf(vk, bf2f((u16)w), a0);
            a1 = fmaf(vk, bf2f((u16)(w >> 16)), a1);
        }
        a0 = fmaxf(a0 * sc_s[j0] + sh_s[j0], 0.f);
        a1 = fmaxf(a1 * sc_s[j0 + 1] + sh_s[j0 + 1], 0.f);
        mid[nn][j0] = a0; mid[nn][j0 + 1] = a1;
    }
    __syncthreads();
    {   // re-stage with wb
        u32* d0 = (u32*)w_s;
        const float2* s0 = (const float2*)wb;
        for (int i = tid; i < DIM * DIM / 2; i += 256) {
            float2 p = s0[i];
            d0[i] = (u32)f2bf(p.x) | ((u32)f2bf(p.y) << 16);
        }
    }
    __syncthreads();
    // phase 2: Linear2 + ReLU -> hout (bf16)
#pragma unroll
    for (int rep = 0; rep < 4; rep++) {
        int nn = rep * 4 + (tid >> 6);
        int node = base + nn;
        float c0 = bb_s[j0], c1 = bb_s[j0 + 1];
#pragma unroll 8
        for (int k = 0; k < DIM; k++) {
            u32 w = *(const u32*)(w_s + k * DIM + j0);
            float mk = mid[nn][k];
            c0 = fmaf(mk, bf2f((u16)w), c0);
            c1 = fmaf(mk, bf2f((u16)(w >> 16)), c1);
        }
        if (node < n) {
            hout[node * DIM + j0]     = f2bf(fmaxf(c0, 0.f));
            hout[node * DIM + j0 + 1] = f2bf(fmaxf(c1, 0.f));
        }
    }
}

// ------------- pool: pooled[g][0:128]=sum h1, [128:256]=sum h2 ----------------
__global__ __launch_bounds__(256) void k_pool(const int* __restrict__ batch,
                                              const u16* __restrict__ h1,
                                              const u16* __restrict__ h2,
                                              float* __restrict__ pool) {
    int g = blockIdx.x;
    int tid = threadIdx.x;
    int lo = 0, hi = N_NODES;
    while (lo < hi) { int m = (lo + hi) >> 1; if (batch[m] < g) lo = m + 1; else hi = m; }
    int start = lo;
    hi = N_NODES;
    while (lo < hi) { int m = (lo + hi) >> 1; if (batch[m] < g + 1) lo = m + 1; else hi = m; }
    int end = lo;
    const u16* h = (tid < DIM) ? h1 : h2;
    int j = tid & 127;
    float acc = 0.f;
    for (int i = start; i < end; i++) acc += bf2f(h[i * DIM + j]);
    pool[g * 256 + tid] = acc;
}

// ------------- head1: hg = relu(pool @ wl1 + bl1)  [500 x 128] ----------------
__global__ __launch_bounds__(256) void k_head1(const float* __restrict__ pool,
                                               const float* __restrict__ wl1,
                                               const float* __restrict__ bl1,
                                               float* __restrict__ hg) {
    int gid = blockIdx.x * 256 + threadIdx.x;
    if (gid >= N_GR * DIM) return;
    int g = gid >> 7, j = gid & 127;
    float acc = bl1[j];
    const float* p = pool + g * 256;
#pragma unroll 4
    for (int k = 0; k < 256; k++) acc = fmaf(p[k], wl1[k * DIM + j], acc);
    hg[gid] = fmaxf(acc, 0.f);
}

// ------------- head2: out = hg @ wl2 + bl2  [500 x 10], f32 -------------------
__global__ __launch_bounds__(256) void k_head2(const float* __restrict__ hg,
                                               const float* __restrict__ wl2,
                                               const float* __restrict__ bl2,
                                               float* __restrict__ out) {
    int gid = blockIdx.x * 256 + threadIdx.x;
    if (gid >= N_GR * N_OUT) return;
    int g = gid / N_OUT, o = gid - g * N_OUT;
    float acc = bl2[o];
    const float* h = hg + g * DIM;
#pragma unroll 4
    for (int k = 0; k < DIM; k++) acc = fmaf(h[k], wl2[k * N_OUT + o], acc);
    out[gid] = acc;
}

extern "C" void kernel_launch(void* const* d_in, const int* in_sizes, int n_in,
                              void* d_out, int out_size, void* d_ws, size_t ws_size,
                              hipStream_t stream) {
    const int* x_ids = (const int*)d_in[0];
    const int* edges = (const int*)d_in[1];
    const int* batch = (const int*)d_in[2];
    const float* emb = (const float*)d_in[3];
    const float *w11 = (const float*)d_in[4],  *b11 = (const float*)d_in[5];
    const float *g1  = (const float*)d_in[6],  *be1 = (const float*)d_in[7];
    const float *m1  = (const float*)d_in[8],  *v1  = (const float*)d_in[9];
    const float *w12 = (const float*)d_in[10], *b12 = (const float*)d_in[11];
    const float *w21 = (const float*)d_in[12], *b21 = (const float*)d_in[13];
    const float *g2  = (const float*)d_in[14], *be2 = (const float*)d_in[15];
    const float *m2  = (const float*)d_in[16], *v2  = (const float*)d_in[17];
    const float *w22 = (const float*)d_in[18], *b22 = (const float*)d_in[19];
    const float *wl1 = (const float*)d_in[20], *bl1 = (const float*)d_in[21];
    const float *wl2 = (const float*)d_in[22], *bl2 = (const float*)d_in[23];

    const int* src = edges;
    const int* dst = edges + N_EDGES;

    float* out_logits = (float*)d_out;                 // [500*10]
    float* xout = (float*)d_out + N_GR * N_OUT;        // [50000*128], byte off 20000 (16B aligned)

    char* ws = (char*)d_ws;
    float* agg  = (float*)ws;                          // 25,600,000 B
    u16*   h1   = (u16*)(ws + 25600000);               // 12,800,000 B
    u16*   h2   = (u16*)(ws + 38400000);               // 12,800,000 B
    float* pool = (float*)(ws + 51200000);             //    512,000 B
    float* hg   = (float*)(ws + 51712000);             //    256,000 B

    // layer 1
    hipMemsetAsync(agg, 0, (size_t)N_NODES * DIM * 4, stream);
    k_gather<<<(N_NODES * 32) / 256, 256, 0, stream>>>(x_ids, emb, xout);
    k_scatter_f32<<<(N_EDGES * 32) / 256, 256, 0, stream>>>(xout, src, dst, agg);
    k_mlp<false><<<(N_NODES + 15) / 16, 256, 0, stream>>>(xout, agg, w11, b11, g1, be1, m1, v1, w12, b12, h1, N_NODES);
    // layer 2
    hipMemsetAsync(agg, 0, (size_t)N_NODES * DIM * 4, stream);
    k_scatter_bf16<<<(N_EDGES * 16) / 256, 256, 0, stream>>>(h1, src, dst, agg);
    k_mlp<true><<<(N_NODES + 15) / 16, 256, 0, stream>>>(h1, agg, w21, b21, g2, be2, m2, v2, w22, b22, h2, N_NODES);
    // readout
    k_pool<<<N_GR, 256, 0, stream>>>(batch, h1, h2, pool);
    k_head1<<<(N_GR * DIM + 255) / 256, 256, 0, stream>>>(pool, wl1, bl1, hg);
    k_head2<<<(N_GR * N_OUT + 255) / 256, 256, 0, stream>>>(hg, wl2, bl2, out_logits);
}

// Round 4
// 706.566 us; speedup vs baseline: 6.3405x; 6.3405x over previous
//
#include <hip/hip_runtime.h>
#include <hip/hip_bf16.h>

#define N_NODES 50000
#define N_EDGES 800000
#define DIM 128
#define N_GR 500
#define N_OUT 10

typedef unsigned short u16;
typedef unsigned int u32;

__device__ __forceinline__ float bf2f(u16 u) {
    union { u32 i; float f; } c; c.i = ((u32)u) << 16; return c.f;
}
__device__ __forceinline__ u16 f2bf(float f) {
    union { float f; u32 i; } c; c.f = f;
    u32 i = c.i;
    u32 r = i + 0x7FFFu + ((i >> 16) & 1u);
    return (u16)(r >> 16);
}

// ---------------- gather: x = emb[x_ids], f32 copy into d_out ----------------
__global__ __launch_bounds__(256) void k_gather(const int* __restrict__ ids,
                                                const float* __restrict__ emb,
                                                float* __restrict__ xout) {
    int gid = blockIdx.x * 256 + threadIdx.x;          // N*32 threads
    if (gid >= N_NODES * 32) return;
    int node = gid >> 5, seg = gid & 31;
    int id = ids[node];
    float4 v = *(const float4*)(emb + id * DIM + seg * 4);
    *(float4*)(xout + node * DIM + seg * 4) = v;
}

// ---------------- CSR build: histogram -> scan -> fill ----------------
__global__ __launch_bounds__(256) void k_hist(const int* __restrict__ dst, int* __restrict__ deg) {
    int e = blockIdx.x * 256 + threadIdx.x;
    if (e >= N_EDGES) return;
    atomicAdd(&deg[dst[e]], 1);
}

// single block; each thread scans a contiguous chunk
__global__ __launch_bounds__(256) void k_scan(const int* __restrict__ deg,
                                              int* __restrict__ rowptr,
                                              int* __restrict__ cursor) {
    __shared__ int sums[256];
    __shared__ int prefix[256];
    const int CHUNK = (N_NODES + 255) / 256;           // 196
    int tid = threadIdx.x;
    int start = tid * CHUNK;
    int s = 0;
    for (int i = 0; i < CHUNK; i++) { int idx = start + i; if (idx < N_NODES) s += deg[idx]; }
    sums[tid] = s;
    __syncthreads();
    if (tid == 0) { int acc = 0; for (int i = 0; i < 256; i++) { prefix[i] = acc; acc += sums[i]; } }
    __syncthreads();
    int acc = prefix[tid];
    for (int i = 0; i < CHUNK; i++) {
        int idx = start + i;
        if (idx < N_NODES) { rowptr[idx] = acc; cursor[idx] = acc; acc += deg[idx]; }
    }
    if (tid == 255) rowptr[N_NODES] = acc;             // == N_EDGES
}

__global__ __launch_bounds__(256) void k_fill(const int* __restrict__ src,
                                              const int* __restrict__ dst,
                                              int* __restrict__ cursor,
                                              int* __restrict__ ssrc) {
    int e = blockIdx.x * 256 + threadIdx.x;
    if (e >= N_EDGES) return;
    int pos = atomicAdd(&cursor[dst[e]], 1);
    ssrc[pos] = src[e];
}

// ---------- aggregate (gather-style, no atomics): agg[i] = sum x[ssrc[...]] ----------
// one wave per node; lane owns 2 consecutive dims
__global__ __launch_bounds__(256) void k_agg_f32(const float* __restrict__ x,
                                                 const int* __restrict__ rowptr,
                                                 const int* __restrict__ ssrc,
                                                 float* __restrict__ agg) {
    int wave = (blockIdx.x * 256 + threadIdx.x) >> 6;
    if (wave >= N_NODES) return;
    int lane = threadIdx.x & 63;
    int beg = rowptr[wave], end = rowptr[wave + 1];
    float ax = 0.f, ay = 0.f;
    for (int i = beg; i < end; i++) {
        int s = ssrc[i];                                // wave-uniform -> scalar load
        float2 v = *(const float2*)(x + s * DIM + lane * 2);
        ax += v.x; ay += v.y;
    }
    float2 o; o.x = ax; o.y = ay;
    *(float2*)(agg + wave * DIM + lane * 2) = o;
}

__global__ __launch_bounds__(256) void k_agg_bf16(const u16* __restrict__ x,
                                                  const int* __restrict__ rowptr,
                                                  const int* __restrict__ ssrc,
                                                  float* __restrict__ agg) {
    int wave = (blockIdx.x * 256 + threadIdx.x) >> 6;
    if (wave >= N_NODES) return;
    int lane = threadIdx.x & 63;
    int beg = rowptr[wave], end = rowptr[wave + 1];
    float ax = 0.f, ay = 0.f;
    for (int i = beg; i < end; i++) {
        int s = ssrc[i];
        u32 v = *(const u32*)(x + s * DIM + lane * 2);
        ax += bf2f((u16)v); ay += bf2f((u16)(v >> 16));
    }
    float2 o; o.x = ax; o.y = ay;
    *(float2*)(agg + wave * DIM + lane * 2) = o;
}

// ------- fused GIN MLP: h = relu( relu(bn((x+agg)@wa+ba)) @ wb + bb ) ---------
// weights f32 in HBM -> bf16 in LDS (32K), + vbuf 8K + mid 8K + 2K = 51.2K LDS
template<bool BF16IN>
__global__ __launch_bounds__(256) void k_mlp(const void* __restrict__ xin_,
                                             const float* __restrict__ agg,
                                             const float* __restrict__ wa, const float* __restrict__ ba,
                                             const float* __restrict__ gg, const float* __restrict__ be,
                                             const float* __restrict__ mm, const float* __restrict__ vv,
                                             const float* __restrict__ wb, const float* __restrict__ bb,
                                             u16* __restrict__ hout, int n) {
    __shared__ u16 w_s[DIM * DIM];                     // 32 KB (wa, then wb)
    __shared__ float sc_s[DIM], sh_s[DIM], ba_s[DIM], bb_s[DIM];
    __shared__ float vbuf[16][DIM];                    // 8 KB
    __shared__ float mid[16][DIM];                     // 8 KB
    int tid = threadIdx.x;

    {   // stage wa into LDS as packed bf16 pairs
        u32* d0 = (u32*)w_s;
        const float2* s0 = (const float2*)wa;
        for (int i = tid; i < DIM * DIM / 2; i += 256) {
            float2 p = s0[i];
            d0[i] = (u32)f2bf(p.x) | ((u32)f2bf(p.y) << 16);
        }
    }
    if (tid < DIM) {
        float s = gg[tid] * rsqrtf(vv[tid] + 1e-5f);
        sc_s[tid] = s;
        sh_s[tid] = be[tid] - mm[tid] * s;
        ba_s[tid] = ba[tid];
        bb_s[tid] = bb[tid];
    }
    int base = blockIdx.x * 16;
    for (int i = tid; i < 16 * DIM; i += 256) {
        int nn = i >> 7, k = i & 127;
        int node = base + nn;
        float val = 0.f;
        if (node < n) {
            float xv = BF16IN ? bf2f(((const u16*)xin_)[node * DIM + k])
                              : ((const float*)xin_)[node * DIM + k];
            val = xv + agg[node * DIM + k];
        }
        vbuf[nn][k] = val;
    }
    __syncthreads();

    int j0 = (tid & 63) * 2;
    // phase 1: Linear1 + BN + ReLU -> mid (wave w handles rows w,4+w,8+w,12+w)
#pragma unroll
    for (int rep = 0; rep < 4; rep++) {
        int nn = rep * 4 + (tid >> 6);
        float a0 = ba_s[j0], a1 = ba_s[j0 + 1];
#pragma unroll 8
        for (int k = 0; k < DIM; k++) {
            u32 w = *(const u32*)(w_s + k * DIM + j0);
            float vk = vbuf[nn][k];
            a0 = fmaf(vk, bf2f((u16)w), a0);
            a1 = fmaf(vk, bf2f((u16)(w >> 16)), a1);
        }
        a0 = fmaxf(a0 * sc_s[j0] + sh_s[j0], 0.f);
        a1 = fmaxf(a1 * sc_s[j0 + 1] + sh_s[j0 + 1], 0.f);
        mid[nn][j0] = a0; mid[nn][j0 + 1] = a1;
    }
    __syncthreads();
    {   // re-stage with wb
        u32* d0 = (u32*)w_s;
        const float2* s0 = (const float2*)wb;
        for (int i = tid; i < DIM * DIM / 2; i += 256) {
            float2 p = s0[i];
            d0[i] = (u32)f2bf(p.x) | ((u32)f2bf(p.y) << 16);
        }
    }
    __syncthreads();
    // phase 2: Linear2 + ReLU -> hout (bf16)
#pragma unroll
    for (int rep = 0; rep < 4; rep++) {
        int nn = rep * 4 + (tid >> 6);
        int node = base + nn;
        float c0 = bb_s[j0], c1 = bb_s[j0 + 1];
#pragma unroll 8
        for (int k = 0; k < DIM; k++) {
            u32 w = *(const u32*)(w_s + k * DIM + j0);
            float mk = mid[nn][k];
            c0 = fmaf(mk, bf2f((u16)w), c0);
            c1 = fmaf(mk, bf2f((u16)(w >> 16)), c1);
        }
        if (node < n) {
            hout[node * DIM + j0]     = f2bf(fmaxf(c0, 0.f));
            hout[node * DIM + j0 + 1] = f2bf(fmaxf(c1, 0.f));
        }
    }
}

// ------------- pool: pooled[g][0:128]=sum h1, [128:256]=sum h2 ----------------
__global__ __launch_bounds__(256) void k_pool(const int* __restrict__ batch,
                                              const u16* __restrict__ h1,
                                              const u16* __restrict__ h2,
                                              float* __restrict__ pool) {
    int g = blockIdx.x;
    int tid = threadIdx.x;
    int lo = 0, hi = N_NODES;
    while (lo < hi) { int m = (lo + hi) >> 1; if (batch[m] < g) lo = m + 1; else hi = m; }
    int start = lo;
    hi = N_NODES;
    while (lo < hi) { int m = (lo + hi) >> 1; if (batch[m] < g + 1) lo = m + 1; else hi = m; }
    int end = lo;
    const u16* h = (tid < DIM) ? h1 : h2;
    int j = tid & 127;
    float acc = 0.f;
    for (int i = start; i < end; i++) acc += bf2f(h[i * DIM + j]);
    pool[g * 256 + tid] = acc;
}

// ------------- head1: hg = relu(pool @ wl1 + bl1)  [500 x 128] ----------------
__global__ __launch_bounds__(256) void k_head1(const float* __restrict__ pool,
                                               const float* __restrict__ wl1,
                                               const float* __restrict__ bl1,
                                               float* __restrict__ hg) {
    int gid = blockIdx.x * 256 + threadIdx.x;
    if (gid >= N_GR * DIM) return;
    int g = gid >> 7, j = gid & 127;
    float acc = bl1[j];
    const float* p = pool + g * 256;
#pragma unroll 4
    for (int k = 0; k < 256; k++) acc = fmaf(p[k], wl1[k * DIM + j], acc);
    hg[gid] = fmaxf(acc, 0.f);
}

// ------------- head2: out = hg @ wl2 + bl2  [500 x 10], f32 -------------------
__global__ __launch_bounds__(256) void k_head2(const float* __restrict__ hg,
                                               const float* __restrict__ wl2,
                                               const float* __restrict__ bl2,
                                               float* __restrict__ out) {
    int gid = blockIdx.x * 256 + threadIdx.x;
    if (gid >= N_GR * N_OUT) return;
    int g = gid / N_OUT, o = gid - g * N_OUT;
    float acc = bl2[o];
    const float* h = hg + g * DIM;
#pragma unroll 4
    for (int k = 0; k < DIM; k++) acc = fmaf(h[k], wl2[k * N_OUT + o], acc);
    out[gid] = acc;
}

extern "C" void kernel_launch(void* const* d_in, const int* in_sizes, int n_in,
                              void* d_out, int out_size, void* d_ws, size_t ws_size,
                              hipStream_t stream) {
    const int* x_ids = (const int*)d_in[0];
    const int* edges = (const int*)d_in[1];
    const int* batch = (const int*)d_in[2];
    const float* emb = (const float*)d_in[3];
    const float *w11 = (const float*)d_in[4],  *b11 = (const float*)d_in[5];
    const float *g1  = (const float*)d_in[6],  *be1 = (const float*)d_in[7];
    const float *m1  = (const float*)d_in[8],  *v1  = (const float*)d_in[9];
    const float *w12 = (const float*)d_in[10], *b12 = (const float*)d_in[11];
    const float *w21 = (const float*)d_in[12], *b21 = (const float*)d_in[13];
    const float *g2  = (const float*)d_in[14], *be2 = (const float*)d_in[15];
    const float *m2  = (const float*)d_in[16], *v2  = (const float*)d_in[17];
    const float *w22 = (const float*)d_in[18], *b22 = (const float*)d_in[19];
    const float *wl1 = (const float*)d_in[20], *bl1 = (const float*)d_in[21];
    const float *wl2 = (const float*)d_in[22], *bl2 = (const float*)d_in[23];

    const int* src = edges;
    const int* dst = edges + N_EDGES;

    float* out_logits = (float*)d_out;                 // [500*10]
    float* xout = (float*)d_out + N_GR * N_OUT;        // [50000*128], byte off 20000 (16B aligned)

    char* ws = (char*)d_ws;
    float* agg    = (float*)ws;                        // 25,600,000 B
    u16*   h1     = (u16*)(ws + 25600000);             // 12,800,000 B
    u16*   h2     = (u16*)(ws + 38400000);             // 12,800,000 B
    float* pool   = (float*)(ws + 51200000);           //    512,000 B
    float* hg     = (float*)(ws + 51712000);           //    256,000 B
    int*   deg    = (int*)(ws + 51968000);             //    200,000 B
    int*   rowptr = (int*)(ws + 52168000);             //    200,016 B (50001 ints)
    int*   cursor = (int*)(ws + 52368016);             //    200,000 B
    int*   ssrc   = (int*)(ws + 52568016);             //  3,200,000 B  (ends 55.77 MB)

    // ---- CSR build (once; shared by both layers) ----
    hipMemsetAsync(deg, 0, (size_t)N_NODES * 4, stream);
    k_hist<<<(N_EDGES + 255) / 256, 256, 0, stream>>>(dst, deg);
    k_scan<<<1, 256, 0, stream>>>(deg, rowptr, cursor);
    k_fill<<<(N_EDGES + 255) / 256, 256, 0, stream>>>(src, dst, cursor, ssrc);

    // ---- layer 1 ----
    k_gather<<<(N_NODES * 32) / 256, 256, 0, stream>>>(x_ids, emb, xout);
    k_agg_f32<<<(N_NODES * 64 + 255) / 256, 256, 0, stream>>>(xout, rowptr, ssrc, agg);
    k_mlp<false><<<(N_NODES + 15) / 16, 256, 0, stream>>>(xout, agg, w11, b11, g1, be1, m1, v1, w12, b12, h1, N_NODES);
    // ---- layer 2 ----
    k_agg_bf16<<<(N_NODES * 64 + 255) / 256, 256, 0, stream>>>(h1, rowptr, ssrc, agg);
    k_mlp<true><<<(N_NODES + 15) / 16, 256, 0, stream>>>(h1, agg, w21, b21, g2, be2, m2, v2, w22, b22, h2, N_NODES);
    // ---- readout ----
    k_pool<<<N_GR, 256, 0, stream>>>(batch, h1, h2, pool);
    k_head1<<<(N_GR * DIM + 255) / 256, 256, 0, stream>>>(pool, wl1, bl1, hg);
    k_head2<<<(N_GR * N_OUT + 255) / 256, 256, 0, stream>>>(hg, wl2, bl2, out_logits);
}

// Round 5
// 396.079 us; speedup vs baseline: 11.3108x; 1.7839x over previous
//
#include <hip/hip_runtime.h>
#include <hip/hip_bf16.h>

#define N_NODES 50000
#define N_EDGES 800000
#define DIM 128
#define N_GR 500
#define N_OUT 10

typedef unsigned short u16;
typedef unsigned int u32;
typedef __attribute__((ext_vector_type(8))) short bf16x8;
typedef __attribute__((ext_vector_type(4))) float f32x4;

#define MFMA16(a, b, c) __builtin_amdgcn_mfma_f32_16x16x32_bf16(a, b, c, 0, 0, 0)

__device__ __forceinline__ float bf2f(u16 u) {
    union { u32 i; float f; } c; c.i = ((u32)u) << 16; return c.f;
}
__device__ __forceinline__ u16 f2bf(float f) {
    union { float f; u32 i; } c; c.f = f;
    u32 i = c.i;
    u32 r = i + 0x7FFFu + ((i >> 16) & 1u);
    return (u16)(r >> 16);
}

// ---------------- gather: x = emb[x_ids], f32 copy into d_out ----------------
__global__ __launch_bounds__(256) void k_gather(const int* __restrict__ ids,
                                                const float* __restrict__ emb,
                                                float* __restrict__ xout) {
    int gid = blockIdx.x * 256 + threadIdx.x;          // N*32 threads
    if (gid >= N_NODES * 32) return;
    int node = gid >> 5, seg = gid & 31;
    int id = ids[node];
    float4 v = *(const float4*)(emb + id * DIM + seg * 4);
    *(float4*)(xout + node * DIM + seg * 4) = v;
}

// ---------------- CSR build: histogram -> 3-stage scan -> fill ----------------
__global__ __launch_bounds__(256) void k_hist(const int* __restrict__ dst, int* __restrict__ deg) {
    int e = blockIdx.x * 256 + threadIdx.x;
    if (e >= N_EDGES) return;
    atomicAdd(&deg[dst[e]], 1);
}

__global__ __launch_bounds__(256) void k_scan1(const int* __restrict__ deg, int* __restrict__ bsum) {
    int t = threadIdx.x, b = blockIdx.x;
    int idx = b * 256 + t;
    int v = (idx < N_NODES) ? deg[idx] : 0;
#pragma unroll
    for (int o = 32; o > 0; o >>= 1) v += __shfl_down(v, o, 64);
    __shared__ int wsum[4];
    if ((t & 63) == 0) wsum[t >> 6] = v;
    __syncthreads();
    if (t == 0) bsum[b] = wsum[0] + wsum[1] + wsum[2] + wsum[3];
}

__global__ __launch_bounds__(256) void k_scan2(const int* __restrict__ bsum, int* __restrict__ bpre) {
    __shared__ int s[256];
    int t = threadIdx.x;
    int v = (t < 196) ? bsum[t] : 0;
    s[t] = v; __syncthreads();
    for (int o = 1; o < 256; o <<= 1) {
        int x = (t >= o) ? s[t - o] : 0;
        __syncthreads();
        s[t] += x;
        __syncthreads();
    }
    if (t < 196) bpre[t] = s[t] - v;                   // exclusive prefix
}

__global__ __launch_bounds__(256) void k_scan3(const int* __restrict__ deg,
                                               const int* __restrict__ bpre,
                                               int* __restrict__ rowptr,
                                               int* __restrict__ cursor) {
    __shared__ int s[256];
    int t = threadIdx.x, b = blockIdx.x;
    int idx = b * 256 + t;
    int v = (idx < N_NODES) ? deg[idx] : 0;
    s[t] = v; __syncthreads();
    for (int o = 1; o < 256; o <<= 1) {
        int x = (t >= o) ? s[t - o] : 0;
        __syncthreads();
        s[t] += x;
        __syncthreads();
    }
    int ex = bpre[b] + s[t] - v;
    if (idx < N_NODES) { rowptr[idx] = ex; cursor[idx] = ex; }
    if (idx == N_NODES - 1) rowptr[N_NODES] = ex + v;
}

__global__ __launch_bounds__(256) void k_fill(const int* __restrict__ src,
                                              const int* __restrict__ dst,
                                              int* __restrict__ cursor,
                                              int* __restrict__ ssrc) {
    int e = blockIdx.x * 256 + threadIdx.x;
    if (e >= N_EDGES) return;
    int pos = atomicAdd(&cursor[dst[e]], 1);
    ssrc[pos] = src[e];
}

// ---- prep: W[k][j] f32 -> wT bf16, j-major rows (256B), XOR-swizzled, in ws ----
// dest byte layout: j*256 + ((2k) ^ ((j&7)<<4))  -- matches k_mlp's ds_read_b128 frags
__global__ __launch_bounds__(256) void k_prep(const float* __restrict__ w11, const float* __restrict__ w12,
                                              const float* __restrict__ w21, const float* __restrict__ w22,
                                              u16* __restrict__ out) {
    int g = blockIdx.x * 256 + threadIdx.x;            // 4 * 8192 threads
    if (g >= 4 * 8192) return;
    int mat = g >> 13, r = g & 8191;
    int j = r & 127, k0 = (r >> 7) * 2;
    const float* w = (mat == 0) ? w11 : (mat == 1) ? w12 : (mat == 2) ? w21 : w22;
    float v0 = w[k0 * DIM + j];
    float v1 = w[(k0 + 1) * DIM + j];
    u32 p = (u32)f2bf(v0) | ((u32)f2bf(v1) << 16);
    char* base = (char*)(out + mat * 16384);
    *(u32*)(base + j * 256 + ((2 * k0) ^ ((j & 7) << 4))) = p;
}

// ---------- aggregate (gather-style, no atomics): agg[i] = sum x[ssrc[...]] ----------
__global__ __launch_bounds__(256) void k_agg_f32(const float* __restrict__ x,
                                                 const int* __restrict__ rowptr,
                                                 const int* __restrict__ ssrc,
                                                 float* __restrict__ agg) {
    int wave = (blockIdx.x * 256 + threadIdx.x) >> 6;
    if (wave >= N_NODES) return;
    int lane = threadIdx.x & 63;
    int beg = rowptr[wave], end = rowptr[wave + 1];
    float ax = 0.f, ay = 0.f;
    for (int i = beg; i < end; i++) {
        int s = ssrc[i];
        float2 v = *(const float2*)(x + s * DIM + lane * 2);
        ax += v.x; ay += v.y;
    }
    float2 o; o.x = ax; o.y = ay;
    *(float2*)(agg + wave * DIM + lane * 2) = o;
}

__global__ __launch_bounds__(256) void k_agg_bf16(const u16* __restrict__ x,
                                                  const int* __restrict__ rowptr,
                                                  const int* __restrict__ ssrc,
                                                  float* __restrict__ agg) {
    int wave = (blockIdx.x * 256 + threadIdx.x) >> 6;
    if (wave >= N_NODES) return;
    int lane = threadIdx.x & 63;
    int beg = rowptr[wave], end = rowptr[wave + 1];
    float ax = 0.f, ay = 0.f;
    for (int i = beg; i < end; i++) {
        int s = ssrc[i];
        u32 v = *(const u32*)(x + s * DIM + lane * 2);
        ax += bf2f((u16)v); ay += bf2f((u16)(v >> 16));
    }
    float2 o; o.x = ax; o.y = ay;
    *(float2*)(agg + wave * DIM + lane * 2) = o;
}

// ------- fused GIN MLP via MFMA: h = relu( relu(bn((x+agg)@wa+ba)) @ wb + bb ) -------
// 32 nodes/block, 4 waves; wave w owns N-cols [32w,32w+32) x all 32 nodes.
// LDS: w_s 32K (swizzled wT, wa then wb) + act 8K + mid 8K + params 2K = 50K
template<bool BF16IN>
__global__ __launch_bounds__(256) void k_mlp(const void* __restrict__ xin_,
                                             const float* __restrict__ agg,
                                             const u16* __restrict__ wsa, const float* __restrict__ ba,
                                             const float* __restrict__ gg, const float* __restrict__ be,
                                             const float* __restrict__ mm, const float* __restrict__ vv,
                                             const u16* __restrict__ wsb, const float* __restrict__ bb,
                                             u16* __restrict__ hout, int n) {
    __shared__ u16 w_s[16384];                         // 32 KB
    __shared__ u16 act_s[4096];                        // 8 KB: [32 nodes][128 k] swizzled
    __shared__ u16 mid_s[4096];                        // 8 KB
    __shared__ float pA[DIM], pS[DIM], pH[DIM], pB[DIM];
    int tid = threadIdx.x;
    int base = blockIdx.x * 32;

    {   // stage pre-swizzled wa: plain linear copy
        const uint4* s0 = (const uint4*)wsa;
        uint4* d0 = (uint4*)w_s;
        for (int i = tid; i < 2048; i += 256) d0[i] = s0[i];
    }
    if (tid < DIM) {
        float s = gg[tid] * rsqrtf(vv[tid] + 1e-5f);
        pS[tid] = s; pH[tid] = be[tid] - mm[tid] * s;
        pA[tid] = ba[tid]; pB[tid] = bb[tid];
    }
    // stage activations (x + agg) -> bf16, swizzled rows
    for (int i = tid; i < 2048; i += 256) {
        int node = i >> 6, k0 = (i & 63) * 2;
        int gnode = base + node;
        float v0 = 0.f, v1 = 0.f;
        if (gnode < n) {
            if (BF16IN) {
                u32 xv = *(const u32*)((const u16*)xin_ + gnode * DIM + k0);
                v0 = bf2f((u16)xv); v1 = bf2f((u16)(xv >> 16));
            } else {
                float2 xv = *(const float2*)((const float*)xin_ + gnode * DIM + k0);
                v0 = xv.x; v1 = xv.y;
            }
            float2 av = *(const float2*)(agg + gnode * DIM + k0);
            v0 += av.x; v1 += av.y;
        }
        u32 p = (u32)f2bf(v0) | ((u32)f2bf(v1) << 16);
        *(u32*)((char*)act_s + node * 256 + ((2 * k0) ^ ((node & 7) << 4))) = p;
    }
    __syncthreads();

    int lane = tid & 63;
    int wv = tid >> 6;
    int fr = lane & 15;                                // output col within tile
    int fq = lane >> 4;                                // k-subgroup / row-group
    int ntb = wv * 2;                                  // first N-tile of this wave
    int xorv = (fr & 7) << 4;                          // row&7 == fr&7 for all tiles (16|32 multiples)

    f32x4 acc[2][2];
    // ---- phase 1: (act @ wa) + ba -> BN -> ReLU -> mid ----
#pragma unroll
    for (int nt = 0; nt < 2; nt++) {
        float b = pA[(ntb + nt) * 16 + fr];
        f32x4 bb4 = {b, b, b, b};
        acc[0][nt] = bb4; acc[1][nt] = bb4;
    }
#pragma unroll
    for (int kb = 0; kb < 4; kb++) {
        int koff = (kb * 64 + fq * 16) ^ xorv;
        bf16x8 a0 = *(const bf16x8*)((const char*)act_s + fr * 256 + koff);
        bf16x8 a1 = *(const bf16x8*)((const char*)act_s + (16 + fr) * 256 + koff);
        bf16x8 b0 = *(const bf16x8*)((const char*)w_s + (ntb * 16 + fr) * 256 + koff);
        bf16x8 b1 = *(const bf16x8*)((const char*)w_s + ((ntb + 1) * 16 + fr) * 256 + koff);
        acc[0][0] = MFMA16(a0, b0, acc[0][0]);
        acc[0][1] = MFMA16(a0, b1, acc[0][1]);
        acc[1][0] = MFMA16(a1, b0, acc[1][0]);
        acc[1][1] = MFMA16(a1, b1, acc[1][1]);
    }
#pragma unroll
    for (int nt = 0; nt < 2; nt++) {
        int j = (ntb + nt) * 16 + fr;
        float sc = pS[j], sh = pH[j];
#pragma unroll
        for (int mt = 0; mt < 2; mt++)
#pragma unroll
            for (int r = 0; r < 4; r++) {
                int node = mt * 16 + fq * 4 + r;
                float v = fmaxf(acc[mt][nt][r] * sc + sh, 0.f);
                *(u16*)((char*)mid_s + node * 256 + ((2 * j) ^ ((node & 7) << 4))) = f2bf(v);
            }
    }
    __syncthreads();
    {   // restage with wb
        const uint4* s0 = (const uint4*)wsb;
        uint4* d0 = (uint4*)w_s;
        for (int i = tid; i < 2048; i += 256) d0[i] = s0[i];
    }
    __syncthreads();
    // ---- phase 2: (mid @ wb) + bb -> ReLU -> hout ----
#pragma unroll
    for (int nt = 0; nt < 2; nt++) {
        float b = pB[(ntb + nt) * 16 + fr];
        f32x4 bb4 = {b, b, b, b};
        acc[0][nt] = bb4; acc[1][nt] = bb4;
    }
#pragma unroll
    for (int kb = 0; kb < 4; kb++) {
        int koff = (kb * 64 + fq * 16) ^ xorv;
        bf16x8 a0 = *(const bf16x8*)((const char*)mid_s + fr * 256 + koff);
        bf16x8 a1 = *(const bf16x8*)((const char*)mid_s + (16 + fr) * 256 + koff);
        bf16x8 b0 = *(const bf16x8*)((const char*)w_s + (ntb * 16 + fr) * 256 + koff);
        bf16x8 b1 = *(const bf16x8*)((const char*)w_s + ((ntb + 1) * 16 + fr) * 256 + koff);
        acc[0][0] = MFMA16(a0, b0, acc[0][0]);
        acc[0][1] = MFMA16(a0, b1, acc[0][1]);
        acc[1][0] = MFMA16(a1, b0, acc[1][0]);
        acc[1][1] = MFMA16(a1, b1, acc[1][1]);
    }
#pragma unroll
    for (int nt = 0; nt < 2; nt++) {
        int j = (ntb + nt) * 16 + fr;
#pragma unroll
        for (int mt = 0; mt < 2; mt++)
#pragma unroll
            for (int r = 0; r < 4; r++) {
                int node = base + mt * 16 + fq * 4 + r;
                if (node < n) hout[node * DIM + j] = f2bf(fmaxf(acc[mt][nt][r], 0.f));
            }
    }
}

// ------------- pool: pooled[g][0:128]=sum h1, [128:256]=sum h2 ----------------
__global__ __launch_bounds__(256) void k_pool(const int* __restrict__ batch,
                                              const u16* __restrict__ h1,
                                              const u16* __restrict__ h2,
                                              float* __restrict__ pool) {
    int g = blockIdx.x;
    int tid = threadIdx.x;
    int lo = 0, hi = N_NODES;
    while (lo < hi) { int m = (lo + hi) >> 1; if (batch[m] < g) lo = m + 1; else hi = m; }
    int start = lo;
    hi = N_NODES;
    while (lo < hi) { int m = (lo + hi) >> 1; if (batch[m] < g + 1) lo = m + 1; else hi = m; }
    int end = lo;
    const u16* h = (tid < DIM) ? h1 : h2;
    int j = tid & 127;
    float acc = 0.f;
    for (int i = start; i < end; i++) acc += bf2f(h[i * DIM + j]);
    pool[g * 256 + tid] = acc;
}

// ------------- head1: hg = relu(pool @ wl1 + bl1)  [500 x 128] ----------------
__global__ __launch_bounds__(256) void k_head1(const float* __restrict__ pool,
                                               const float* __restrict__ wl1,
                                               const float* __restrict__ bl1,
                                               float* __restrict__ hg) {
    int gid = blockIdx.x * 256 + threadIdx.x;
    if (gid >= N_GR * DIM) return;
    int g = gid >> 7, j = gid & 127;
    float acc = bl1[j];
    const float* p = pool + g * 256;
#pragma unroll 4
    for (int k = 0; k < 256; k++) acc = fmaf(p[k], wl1[k * DIM + j], acc);
    hg[gid] = fmaxf(acc, 0.f);
}

// ------------- head2: out = hg @ wl2 + bl2  [500 x 10], f32 -------------------
__global__ __launch_bounds__(256) void k_head2(const float* __restrict__ hg,
                                               const float* __restrict__ wl2,
                                               const float* __restrict__ bl2,
                                               float* __restrict__ out) {
    int gid = blockIdx.x * 256 + threadIdx.x;
    if (gid >= N_GR * N_OUT) return;
    int g = gid / N_OUT, o = gid - g * N_OUT;
    float acc = bl2[o];
    const float* h = hg + g * DIM;
#pragma unroll 4
    for (int k = 0; k < DIM; k++) acc = fmaf(h[k], wl2[k * N_OUT + o], acc);
    out[gid] = acc;
}

extern "C" void kernel_launch(void* const* d_in, const int* in_sizes, int n_in,
                              void* d_out, int out_size, void* d_ws, size_t ws_size,
                              hipStream_t stream) {
    const int* x_ids = (const int*)d_in[0];
    const int* edges = (const int*)d_in[1];
    const int* batch = (const int*)d_in[2];
    const float* emb = (const float*)d_in[3];
    const float *w11 = (const float*)d_in[4],  *b11 = (const float*)d_in[5];
    const float *g1  = (const float*)d_in[6],  *be1 = (const float*)d_in[7];
    const float *m1  = (const float*)d_in[8],  *v1  = (const float*)d_in[9];
    const float *w12 = (const float*)d_in[10], *b12 = (const float*)d_in[11];
    const float *w21 = (const float*)d_in[12], *b21 = (const float*)d_in[13];
    const float *g2  = (const float*)d_in[14], *be2 = (const float*)d_in[15];
    const float *m2  = (const float*)d_in[16], *v2  = (const float*)d_in[17];
    const float *w22 = (const float*)d_in[18], *b22 = (const float*)d_in[19];
    const float *wl1 = (const float*)d_in[20], *bl1 = (const float*)d_in[21];
    const float *wl2 = (const float*)d_in[22], *bl2 = (const float*)d_in[23];

    const int* src = edges;
    const int* dst = edges + N_EDGES;

    float* out_logits = (float*)d_out;                 // [500*10]
    float* xout = (float*)d_out + N_GR * N_OUT;        // [50000*128]

    char* ws = (char*)d_ws;
    float* agg    = (float*)ws;                        // 25,600,000 B
    u16*   h1     = (u16*)(ws + 25600000);             // 12,800,000 B
    u16*   h2     = (u16*)(ws + 38400000);             // 12,800,000 B
    float* pool   = (float*)(ws + 51200000);           //    512,000 B (scan scratch overlaps: dead by k_pool time)
    int*   bsum   = (int*)(ws + 51200000);             //        784 B (temporal overlap w/ pool)
    int*   bpre   = (int*)(ws + 51204096);             //        784 B
    float* hg     = (float*)(ws + 51712000);           //    256,000 B
    int*   deg    = (int*)(ws + 51968000);             //    200,000 B
    int*   rowptr = (int*)(ws + 52168000);             //    200,016 B
    int*   cursor = (int*)(ws + 52368016);             //    200,000 B (reused for wsz after k_fill)
    u16*   wsz    = (u16*)(ws + 52368016);             //    131,072 B: 4x swizzled wT (after k_fill)
    int*   ssrc   = (int*)(ws + 52568016);             //  3,200,000 B

    u16* wsz1a = wsz;            u16* wsz1b = wsz + 16384;
    u16* wsz2a = wsz + 32768;    u16* wsz2b = wsz + 49152;

    // ---- CSR build (once; shared by both layers) ----
    hipMemsetAsync(deg, 0, (size_t)N_NODES * 4, stream);
    k_hist<<<(N_EDGES + 255) / 256, 256, 0, stream>>>(dst, deg);
    k_scan1<<<196, 256, 0, stream>>>(deg, bsum);
    k_scan2<<<1, 256, 0, stream>>>(bsum, bpre);
    k_scan3<<<196, 256, 0, stream>>>(deg, bpre, rowptr, cursor);
    k_fill<<<(N_EDGES + 255) / 256, 256, 0, stream>>>(src, dst, cursor, ssrc);
    // cursor is dead from here; stage swizzled weights into its space
    k_prep<<<128, 256, 0, stream>>>(w11, w12, w21, w22, wsz);

    // ---- layer 1 ----
    k_gather<<<(N_NODES * 32) / 256, 256, 0, stream>>>(x_ids, emb, xout);
    k_agg_f32<<<(N_NODES * 64 + 255) / 256, 256, 0, stream>>>(xout, rowptr, ssrc, agg);
    k_mlp<false><<<(N_NODES + 31) / 32, 256, 0, stream>>>(xout, agg, wsz1a, b11, g1, be1, m1, v1, wsz1b, b12, h1, N_NODES);
    // ---- layer 2 ----
    k_agg_bf16<<<(N_NODES * 64 + 255) / 256, 256, 0, stream>>>(h1, rowptr, ssrc, agg);
    k_mlp<true><<<(N_NODES + 31) / 32, 256, 0, stream>>>(h1, agg, wsz2a, b21, g2, be2, m2, v2, wsz2b, b22, h2, N_NODES);
    // ---- readout ----
    k_pool<<<N_GR, 256, 0, stream>>>(batch, h1, h2, pool);
    k_head1<<<(N_GR * DIM + 255) / 256, 256, 0, stream>>>(pool, wl1, bl1, hg);
    k_head2<<<(N_GR * N_OUT + 255) / 256, 256, 0, stream>>>(hg, wl2, bl2, out_logits);
}

// Round 6
// 347.442 us; speedup vs baseline: 12.8941x; 1.1400x over previous
//
#include <hip/hip_runtime.h>
#include <hip/hip_bf16.h>

#define N_NODES 50000
#define N_EDGES 800000
#define DIM 128
#define N_GR 500
#define N_OUT 10

typedef unsigned short u16;
typedef unsigned int u32;
typedef __attribute__((ext_vector_type(8))) short bf16x8;
typedef __attribute__((ext_vector_type(4))) float f32x4;

#define MFMA16(a, b, c) __builtin_amdgcn_mfma_f32_16x16x32_bf16(a, b, c, 0, 0, 0)

__device__ __forceinline__ float bf2f(u16 u) {
    union { u32 i; float f; } c; c.i = ((u32)u) << 16; return c.f;
}
__device__ __forceinline__ u16 f2bf(float f) {
    union { float f; u32 i; } c; c.f = f;
    u32 i = c.i;
    u32 r = i + 0x7FFFu + ((i >> 16) & 1u);
    return (u16)(r >> 16);
}

// ---------------- gather: x = emb[x_ids], f32 copy into d_out ----------------
__global__ __launch_bounds__(256) void k_gather(const int* __restrict__ ids,
                                                const float* __restrict__ emb,
                                                float* __restrict__ xout) {
    int gid = blockIdx.x * 256 + threadIdx.x;          // N*32 threads
    if (gid >= N_NODES * 32) return;
    int node = gid >> 5, seg = gid & 31;
    int id = ids[node];
    float4 v = *(const float4*)(emb + id * DIM + seg * 4);
    *(float4*)(xout + node * DIM + seg * 4) = v;
}

// ---------------- embbf: emb f32 -> bf16 (500x128 = 128 KB, L2-resident) -----
__global__ __launch_bounds__(256) void k_embf(const float* __restrict__ emb,
                                              u16* __restrict__ embbf) {
    int i = blockIdx.x * 256 + threadIdx.x;            // 32000 u32 elems
    if (i >= N_GR * DIM / 2) return;                   // V==500==N_GR
    float2 p = *(const float2*)(emb + i * 2);
    ((u32*)embbf)[i] = (u32)f2bf(p.x) | ((u32)f2bf(p.y) << 16);
}

// ---------------- CSR build: histogram -> 3-stage scan -> fill ----------------
__global__ __launch_bounds__(256) void k_hist(const int* __restrict__ dst, int* __restrict__ deg) {
    int e = blockIdx.x * 256 + threadIdx.x;
    if (e >= N_EDGES) return;
    atomicAdd(&deg[dst[e]], 1);
}

__global__ __launch_bounds__(256) void k_scan1(const int* __restrict__ deg, int* __restrict__ bsum) {
    int t = threadIdx.x, b = blockIdx.x;
    int idx = b * 256 + t;
    int v = (idx < N_NODES) ? deg[idx] : 0;
#pragma unroll
    for (int o = 32; o > 0; o >>= 1) v += __shfl_down(v, o, 64);
    __shared__ int wsum[4];
    if ((t & 63) == 0) wsum[t >> 6] = v;
    __syncthreads();
    if (t == 0) bsum[b] = wsum[0] + wsum[1] + wsum[2] + wsum[3];
}

__global__ __launch_bounds__(256) void k_scan2(const int* __restrict__ bsum, int* __restrict__ bpre) {
    __shared__ int s[256];
    int t = threadIdx.x;
    int v = (t < 196) ? bsum[t] : 0;
    s[t] = v; __syncthreads();
    for (int o = 1; o < 256; o <<= 1) {
        int x = (t >= o) ? s[t - o] : 0;
        __syncthreads();
        s[t] += x;
        __syncthreads();
    }
    if (t < 196) bpre[t] = s[t] - v;                   // exclusive prefix
}

__global__ __launch_bounds__(256) void k_scan3(const int* __restrict__ deg,
                                               const int* __restrict__ bpre,
                                               int* __restrict__ rowptr,
                                               int* __restrict__ cursor) {
    __shared__ int s[256];
    int t = threadIdx.x, b = blockIdx.x;
    int idx = b * 256 + t;
    int v = (idx < N_NODES) ? deg[idx] : 0;
    s[t] = v; __syncthreads();
    for (int o = 1; o < 256; o <<= 1) {
        int x = (t >= o) ? s[t - o] : 0;
        __syncthreads();
        s[t] += x;
        __syncthreads();
    }
    int ex = bpre[b] + s[t] - v;
    if (idx < N_NODES) { rowptr[idx] = ex; cursor[idx] = ex; }
    if (idx == N_NODES - 1) rowptr[N_NODES] = ex + v;
}

// fill CSR: ssrc[pos]=src (for layer 2) and id16[pos]=x_ids[src] (for layer 1)
__global__ __launch_bounds__(256) void k_fill(const int* __restrict__ src,
                                              const int* __restrict__ dst,
                                              const int* __restrict__ xids,
                                              int* __restrict__ cursor,
                                              int* __restrict__ ssrc,
                                              u16* __restrict__ id16) {
    int e = blockIdx.x * 256 + threadIdx.x;
    if (e >= N_EDGES) return;
    int s = src[e];
    int pos = atomicAdd(&cursor[dst[e]], 1);
    ssrc[pos] = s;
    id16[pos] = (u16)xids[s];
}

// ---- prep: W[k][j] f32 -> wT bf16, j-major rows (256B), XOR-swizzled, in ws ----
__global__ __launch_bounds__(256) void k_prep(const float* __restrict__ w11, const float* __restrict__ w12,
                                              const float* __restrict__ w21, const float* __restrict__ w22,
                                              u16* __restrict__ out) {
    int g = blockIdx.x * 256 + threadIdx.x;            // 4 * 8192 threads
    if (g >= 4 * 8192) return;
    int mat = g >> 13, r = g & 8191;
    int j = r & 127, k0 = (r >> 7) * 2;
    const float* w = (mat == 0) ? w11 : (mat == 1) ? w12 : (mat == 2) ? w21 : w22;
    float v0 = w[k0 * DIM + j];
    float v1 = w[(k0 + 1) * DIM + j];
    u32 p = (u32)f2bf(v0) | ((u32)f2bf(v1) << 16);
    char* base = (char*)(out + mat * 16384);
    *(u32*)(base + j * 256 + ((2 * k0) ^ ((j & 7) << 4))) = p;
}

// ---- layer-1 aggregate from the 128 KB embbf table (L2-resident reads) ------
__global__ __launch_bounds__(256) void k_agg_emb(const u16* __restrict__ embbf,
                                                 const u16* __restrict__ id16,
                                                 const int* __restrict__ rowptr,
                                                 float* __restrict__ agg) {
    int wave = (blockIdx.x * 256 + threadIdx.x) >> 6;
    if (wave >= N_NODES) return;
    int lane = threadIdx.x & 63;
    int beg = rowptr[wave], end = rowptr[wave + 1];
    float ax = 0.f, ay = 0.f;
    for (int i = beg; i < end; i++) {
        int id = id16[i];                              // wave-uniform 2B load
        u32 v = *(const u32*)(embbf + id * DIM + lane * 2);
        ax += bf2f((u16)v); ay += bf2f((u16)(v >> 16));
    }
    float2 o; o.x = ax; o.y = ay;
    *(float2*)(agg + wave * DIM + lane * 2) = o;
}

// ---- layer-2 aggregate (gather-style from h1 bf16) --------------------------
__global__ __launch_bounds__(256) void k_agg_bf16(const u16* __restrict__ x,
                                                  const int* __restrict__ rowptr,
                                                  const int* __restrict__ ssrc,
                                                  float* __restrict__ agg) {
    int wave = (blockIdx.x * 256 + threadIdx.x) >> 6;
    if (wave >= N_NODES) return;
    int lane = threadIdx.x & 63;
    int beg = rowptr[wave], end = rowptr[wave + 1];
    float ax = 0.f, ay = 0.f;
    for (int i = beg; i < end; i++) {
        int s = ssrc[i];
        u32 v = *(const u32*)(x + s * DIM + lane * 2);
        ax += bf2f((u16)v); ay += bf2f((u16)(v >> 16));
    }
    float2 o; o.x = ax; o.y = ay;
    *(float2*)(agg + wave * DIM + lane * 2) = o;
}

// ------- fused GIN MLP via MFMA: h = relu( relu(bn((x+agg)@wa+ba)) @ wb + bb ) -------
// GATHER: xin row = embbf[ids[node]] (layer 1), else xin row = xin[node] (layer 2)
template<bool GATHER>
__global__ __launch_bounds__(256) void k_mlp(const u16* __restrict__ xin,
                                             const int* __restrict__ ids,
                                             const float* __restrict__ agg,
                                             const u16* __restrict__ wsa, const float* __restrict__ ba,
                                             const float* __restrict__ gg, const float* __restrict__ be,
                                             const float* __restrict__ mm, const float* __restrict__ vv,
                                             const u16* __restrict__ wsb, const float* __restrict__ bb,
                                             u16* __restrict__ hout, int n) {
    __shared__ u16 w_s[16384];                         // 32 KB
    __shared__ u16 act_s[4096];                        // 8 KB: [32 nodes][128 k] swizzled
    __shared__ u16 mid_s[4096];                        // 8 KB
    __shared__ float pA[DIM], pS[DIM], pH[DIM], pB[DIM];
    int tid = threadIdx.x;
    int base = blockIdx.x * 32;

    {   // stage pre-swizzled wa: plain linear copy
        const uint4* s0 = (const uint4*)wsa;
        uint4* d0 = (uint4*)w_s;
        for (int i = tid; i < 2048; i += 256) d0[i] = s0[i];
    }
    if (tid < DIM) {
        float s = gg[tid] * rsqrtf(vv[tid] + 1e-5f);
        pS[tid] = s; pH[tid] = be[tid] - mm[tid] * s;
        pA[tid] = ba[tid]; pB[tid] = bb[tid];
    }
    // stage activations (x + agg) -> bf16, swizzled rows
    for (int i = tid; i < 2048; i += 256) {
        int node = i >> 6, ku = i & 63;                // ku: u32 index (2 dims)
        int gnode = base + node;
        float v0 = 0.f, v1 = 0.f;
        if (gnode < n) {
            const u16* row = GATHER ? (xin + ids[gnode] * DIM) : (xin + gnode * DIM);
            u32 xv = *(const u32*)(row + ku * 2);
            v0 = bf2f((u16)xv); v1 = bf2f((u16)(xv >> 16));
            float2 av = *(const float2*)(agg + gnode * DIM + ku * 2);
            v0 += av.x; v1 += av.y;
        }
        u32 p = (u32)f2bf(v0) | ((u32)f2bf(v1) << 16);
        *(u32*)((char*)act_s + node * 256 + ((4 * ku) ^ ((node & 7) << 4))) = p;
    }
    __syncthreads();

    int lane = tid & 63;
    int wv = tid >> 6;
    int fr = lane & 15;                                // output col within tile
    int fq = lane >> 4;                                // k-subgroup / row-group
    int ntb = wv * 2;                                  // first N-tile of this wave
    int xorv = (fr & 7) << 4;

    f32x4 acc[2][2];
    // ---- phase 1: (act @ wa) + ba -> BN -> ReLU -> mid ----
#pragma unroll
    for (int nt = 0; nt < 2; nt++) {
        float b = pA[(ntb + nt) * 16 + fr];
        f32x4 bb4 = {b, b, b, b};
        acc[0][nt] = bb4; acc[1][nt] = bb4;
    }
#pragma unroll
    for (int kb = 0; kb < 4; kb++) {
        int koff = (kb * 64 + fq * 16) ^ xorv;
        bf16x8 a0 = *(const bf16x8*)((const char*)act_s + fr * 256 + koff);
        bf16x8 a1 = *(const bf16x8*)((const char*)act_s + (16 + fr) * 256 + koff);
        bf16x8 b0 = *(const bf16x8*)((const char*)w_s + (ntb * 16 + fr) * 256 + koff);
        bf16x8 b1 = *(const bf16x8*)((const char*)w_s + ((ntb + 1) * 16 + fr) * 256 + koff);
        acc[0][0] = MFMA16(a0, b0, acc[0][0]);
        acc[0][1] = MFMA16(a0, b1, acc[0][1]);
        acc[1][0] = MFMA16(a1, b0, acc[1][0]);
        acc[1][1] = MFMA16(a1, b1, acc[1][1]);
    }
#pragma unroll
    for (int nt = 0; nt < 2; nt++) {
        int j = (ntb + nt) * 16 + fr;
        float sc = pS[j], sh = pH[j];
#pragma unroll
        for (int mt = 0; mt < 2; mt++)
#pragma unroll
            for (int r = 0; r < 4; r++) {
                int node = mt * 16 + fq * 4 + r;
                float v = fmaxf(acc[mt][nt][r] * sc + sh, 0.f);
                *(u16*)((char*)mid_s + node * 256 + ((2 * j) ^ ((node & 7) << 4))) = f2bf(v);
            }
    }
    __syncthreads();
    {   // restage with wb
        const uint4* s0 = (const uint4*)wsb;
        uint4* d0 = (uint4*)w_s;
        for (int i = tid; i < 2048; i += 256) d0[i] = s0[i];
    }
    __syncthreads();
    // ---- phase 2: (mid @ wb) + bb -> ReLU -> hout ----
#pragma unroll
    for (int nt = 0; nt < 2; nt++) {
        float b = pB[(ntb + nt) * 16 + fr];
        f32x4 bb4 = {b, b, b, b};
        acc[0][nt] = bb4; acc[1][nt] = bb4;
    }
#pragma unroll
    for (int kb = 0; kb < 4; kb++) {
        int koff = (kb * 64 + fq * 16) ^ xorv;
        bf16x8 a0 = *(const bf16x8*)((const char*)mid_s + fr * 256 + koff);
        bf16x8 a1 = *(const bf16x8*)((const char*)mid_s + (16 + fr) * 256 + koff);
        bf16x8 b0 = *(const bf16x8*)((const char*)w_s + (ntb * 16 + fr) * 256 + koff);
        bf16x8 b1 = *(const bf16x8*)((const char*)w_s + ((ntb + 1) * 16 + fr) * 256 + koff);
        acc[0][0] = MFMA16(a0, b0, acc[0][0]);
        acc[0][1] = MFMA16(a0, b1, acc[0][1]);
        acc[1][0] = MFMA16(a1, b0, acc[1][0]);
        acc[1][1] = MFMA16(a1, b1, acc[1][1]);
    }
#pragma unroll
    for (int nt = 0; nt < 2; nt++) {
        int j = (ntb + nt) * 16 + fr;
#pragma unroll
        for (int mt = 0; mt < 2; mt++)
#pragma unroll
            for (int r = 0; r < 4; r++) {
                int node = base + mt * 16 + fq * 4 + r;
                if (node < n) hout[node * DIM + j] = f2bf(fmaxf(acc[mt][nt][r], 0.f));
            }
    }
}

// ------------- pool: pooled[g][0:128]=sum h1, [128:256]=sum h2 ----------------
// 256 threads: half=h1/h2, 64 u32-lanes per half, 2 nodes in flight
__global__ __launch_bounds__(256) void k_pool(const int* __restrict__ batch,
                                              const u16* __restrict__ h1,
                                              const u16* __restrict__ h2,
                                              float* __restrict__ pool) {
    int g = blockIdx.x;
    int tid = threadIdx.x;
    int lo = 0, hi = N_NODES;
    while (lo < hi) { int m = (lo + hi) >> 1; if (batch[m] < g) lo = m + 1; else hi = m; }
    int start = lo;
    hi = N_NODES;
    while (lo < hi) { int m = (lo + hi) >> 1; if (batch[m] < g + 1) lo = m + 1; else hi = m; }
    int end = lo;
    int half = (tid >> 6) & 1;                         // 0: h1, 1: h2
    int ju = tid & 63;                                 // u32 index within 128-dim row
    int par = tid >> 7;                                // node parity
    const u16* h = half ? h2 : h1;
    float a0 = 0.f, a1 = 0.f;
    for (int i = start + par; i < end; i += 2) {
        u32 v = *(const u32*)(h + i * DIM + ju * 2);
        a0 += bf2f((u16)v); a1 += bf2f((u16)(v >> 16));
    }
    __shared__ float2 red[2][128];
    red[par][half * 64 + ju] = make_float2(a0, a1);
    __syncthreads();
    if (tid < 128) {
        float2 r0 = red[0][tid], r1 = red[1][tid];
        pool[g * 256 + tid * 2]     = r0.x + r1.x;
        pool[g * 256 + tid * 2 + 1] = r0.y + r1.y;
    }
}

// ------------- head1: hg = relu(pool @ wl1 + bl1)  [500 x 128] ----------------
__global__ __launch_bounds__(256) void k_head1(const float* __restrict__ pool,
                                               const float* __restrict__ wl1,
                                               const float* __restrict__ bl1,
                                               float* __restrict__ hg) {
    int gid = blockIdx.x * 256 + threadIdx.x;
    if (gid >= N_GR * DIM) return;
    int g = gid >> 7, j = gid & 127;
    float acc = bl1[j];
    const float* p = pool + g * 256;
#pragma unroll 4
    for (int k = 0; k < 256; k++) acc = fmaf(p[k], wl1[k * DIM + j], acc);
    hg[gid] = fmaxf(acc, 0.f);
}

// ------------- head2: out = hg @ wl2 + bl2  [500 x 10], f32 -------------------
__global__ __launch_bounds__(256) void k_head2(const float* __restrict__ hg,
                                               const float* __restrict__ wl2,
                                               const float* __restrict__ bl2,
                                               float* __restrict__ out) {
    int gid = blockIdx.x * 256 + threadIdx.x;
    if (gid >= N_GR * N_OUT) return;
    int g = gid / N_OUT, o = gid - g * N_OUT;
    float acc = bl2[o];
    const float* h = hg + g * DIM;
#pragma unroll 4
    for (int k = 0; k < DIM; k++) acc = fmaf(h[k], wl2[k * N_OUT + o], acc);
    out[gid] = acc;
}

extern "C" void kernel_launch(void* const* d_in, const int* in_sizes, int n_in,
                              void* d_out, int out_size, void* d_ws, size_t ws_size,
                              hipStream_t stream) {
    const int* x_ids = (const int*)d_in[0];
    const int* edges = (const int*)d_in[1];
    const int* batch = (const int*)d_in[2];
    const float* emb = (const float*)d_in[3];
    const float *w11 = (const float*)d_in[4],  *b11 = (const float*)d_in[5];
    const float *g1  = (const float*)d_in[6],  *be1 = (const float*)d_in[7];
    const float *m1  = (const float*)d_in[8],  *v1  = (const float*)d_in[9];
    const float *w12 = (const float*)d_in[10], *b12 = (const float*)d_in[11];
    const float *w21 = (const float*)d_in[12], *b21 = (const float*)d_in[13];
    const float *g2  = (const float*)d_in[14], *be2 = (const float*)d_in[15];
    const float *m2  = (const float*)d_in[16], *v2  = (const float*)d_in[17];
    const float *w22 = (const float*)d_in[18], *b22 = (const float*)d_in[19];
    const float *wl1 = (const float*)d_in[20], *bl1 = (const float*)d_in[21];
    const float *wl2 = (const float*)d_in[22], *bl2 = (const float*)d_in[23];

    const int* src = edges;
    const int* dst = edges + N_EDGES;

    float* out_logits = (float*)d_out;                 // [500*10]
    float* xout = (float*)d_out + N_GR * N_OUT;        // [50000*128]

    char* ws = (char*)d_ws;
    float* agg    = (float*)ws;                        // 25,600,000 B
    u16*   h1     = (u16*)(ws + 25600000);             // 12,800,000 B
    u16*   h2     = (u16*)(ws + 38400000);             // 12,800,000 B
    // embbf/id16 alias the h2 region: both dead before k_mlp<false> writes h2
    u16*   embbf  = (u16*)(ws + 38400000);             //    128,000 B
    u16*   id16   = (u16*)(ws + 38528000);             //  1,600,000 B
    float* pool   = (float*)(ws + 51200000);           //    512,000 B
    int*   bsum   = (int*)(ws + 51200000);             //   (overlaps pool; dead by k_pool)
    int*   bpre   = (int*)(ws + 51204096);
    float* hg     = (float*)(ws + 51712000);           //    256,000 B
    int*   deg    = (int*)(ws + 51968000);             //    200,000 B
    int*   rowptr = (int*)(ws + 52168000);             //    200,016 B
    int*   cursor = (int*)(ws + 52368016);             //    200,000 B (reused for wsz after k_fill)
    u16*   wsz    = (u16*)(ws + 52368016);             //    131,072 B
    int*   ssrc   = (int*)(ws + 52568016);             //  3,200,000 B (ends 55.77 MB)

    u16* wsz1a = wsz;            u16* wsz1b = wsz + 16384;
    u16* wsz2a = wsz + 32768;    u16* wsz2b = wsz + 49152;

    // ---- CSR build (once; shared by both layers) ----
    hipMemsetAsync(deg, 0, (size_t)N_NODES * 4, stream);
    k_hist<<<(N_EDGES + 255) / 256, 256, 0, stream>>>(dst, deg);
    k_scan1<<<196, 256, 0, stream>>>(deg, bsum);
    k_scan2<<<1, 256, 0, stream>>>(bsum, bpre);
    k_scan3<<<196, 256, 0, stream>>>(deg, bpre, rowptr, cursor);
    k_fill<<<(N_EDGES + 255) / 256, 256, 0, stream>>>(src, dst, x_ids, cursor, ssrc, id16);
    // cursor dead; stage swizzled weights + bf16 emb table
    k_prep<<<128, 256, 0, stream>>>(w11, w12, w21, w22, wsz);
    k_embf<<<125, 256, 0, stream>>>(emb, embbf);

    // ---- layer 1 ----
    k_gather<<<(N_NODES * 32) / 256, 256, 0, stream>>>(x_ids, emb, xout);
    k_agg_emb<<<(N_NODES * 64 + 255) / 256, 256, 0, stream>>>(embbf, id16, rowptr, agg);
    k_mlp<true><<<(N_NODES + 31) / 32, 256, 0, stream>>>(embbf, x_ids, agg, wsz1a, b11, g1, be1, m1, v1, wsz1b, b12, h1, N_NODES);
    // ---- layer 2 ----
    k_agg_bf16<<<(N_NODES * 64 + 255) / 256, 256, 0, stream>>>(h1, rowptr, ssrc, agg);
    k_mlp<false><<<(N_NODES + 31) / 32, 256, 0, stream>>>(h1, nullptr, agg, wsz2a, b21, g2, be2, m2, v2, wsz2b, b22, h2, N_NODES);
    // ---- readout ----
    k_pool<<<N_GR, 256, 0, stream>>>(batch, h1, h2, pool);
    k_head1<<<(N_GR * DIM + 255) / 256, 256, 0, stream>>>(pool, wl1, bl1, hg);
    k_head2<<<(N_GR * N_OUT + 255) / 256, 256, 0, stream>>>(hg, wl2, bl2, out_logits);
}

// Round 7
// 287.080 us; speedup vs baseline: 15.6052x; 1.2103x over previous
//
#include <hip/hip_runtime.h>
#include <hip/hip_bf16.h>

#define N_NODES 50000
#define N_EDGES 800000
#define DIM 128
#define N_GR 500
#define N_OUT 10

typedef unsigned short u16;
typedef unsigned int u32;
typedef __attribute__((ext_vector_type(8))) short bf16x8;
typedef __attribute__((ext_vector_type(4))) float f32x4;

#define MFMA16(a, b, c) __builtin_amdgcn_mfma_f32_16x16x32_bf16(a, b, c, 0, 0, 0)

__device__ __forceinline__ float bf2f(u16 u) {
    union { u32 i; float f; } c; c.i = ((u32)u) << 16; return c.f;
}
__device__ __forceinline__ u16 f2bf(float f) {
    union { float f; u32 i; } c; c.f = f;
    u32 i = c.i;
    u32 r = i + 0x7FFFu + ((i >> 16) & 1u);
    return (u16)(r >> 16);
}
__device__ __forceinline__ u32 pack2(float a, float b) {
    return (u32)f2bf(a) | ((u32)f2bf(b) << 16);
}

// ---------------- gather: x = emb[x_ids], f32 copy into d_out ----------------
__global__ __launch_bounds__(256) void k_gather(const int* __restrict__ ids,
                                                const float* __restrict__ emb,
                                                float* __restrict__ xout) {
    int gid = blockIdx.x * 256 + threadIdx.x;          // N*32 threads
    if (gid >= N_NODES * 32) return;
    int node = gid >> 5, seg = gid & 31;
    int id = ids[node];
    float4 v = *(const float4*)(emb + id * DIM + seg * 4);
    *(float4*)(xout + node * DIM + seg * 4) = v;
}

// ---------------- embbf: emb f32 -> bf16 (500x128 = 128 KB, L2-resident) -----
__global__ __launch_bounds__(256) void k_embf(const float* __restrict__ emb,
                                              u16* __restrict__ embbf) {
    int i = blockIdx.x * 256 + threadIdx.x;            // 32000 u32 elems
    if (i >= N_GR * DIM / 2) return;                   // V==500==N_GR
    float2 p = *(const float2*)(emb + i * 2);
    ((u32*)embbf)[i] = pack2(p.x, p.y);
}

// ---------------- CSR build: histogram -> 3-stage scan -> fill ----------------
__global__ __launch_bounds__(256) void k_hist(const int* __restrict__ dst, int* __restrict__ deg) {
    int e = blockIdx.x * 256 + threadIdx.x;
    if (e >= N_EDGES) return;
    atomicAdd(&deg[dst[e]], 1);
}

__global__ __launch_bounds__(256) void k_scan1(const int* __restrict__ deg, int* __restrict__ bsum) {
    int t = threadIdx.x, b = blockIdx.x;
    int idx = b * 256 + t;
    int v = (idx < N_NODES) ? deg[idx] : 0;
#pragma unroll
    for (int o = 32; o > 0; o >>= 1) v += __shfl_down(v, o, 64);
    __shared__ int wsum[4];
    if ((t & 63) == 0) wsum[t >> 6] = v;
    __syncthreads();
    if (t == 0) bsum[b] = wsum[0] + wsum[1] + wsum[2] + wsum[3];
}

__global__ __launch_bounds__(256) void k_scan2(const int* __restrict__ bsum, int* __restrict__ bpre) {
    __shared__ int s[256];
    int t = threadIdx.x;
    int v = (t < 196) ? bsum[t] : 0;
    s[t] = v; __syncthreads();
    for (int o = 1; o < 256; o <<= 1) {
        int x = (t >= o) ? s[t - o] : 0;
        __syncthreads();
        s[t] += x;
        __syncthreads();
    }
    if (t < 196) bpre[t] = s[t] - v;                   // exclusive prefix
}

__global__ __launch_bounds__(256) void k_scan3(const int* __restrict__ deg,
                                               const int* __restrict__ bpre,
                                               int* __restrict__ rowptr,
                                               int* __restrict__ cursor) {
    __shared__ int s[256];
    int t = threadIdx.x, b = blockIdx.x;
    int idx = b * 256 + t;
    int v = (idx < N_NODES) ? deg[idx] : 0;
    s[t] = v; __syncthreads();
    for (int o = 1; o < 256; o <<= 1) {
        int x = (t >= o) ? s[t - o] : 0;
        __syncthreads();
        s[t] += x;
        __syncthreads();
    }
    int ex = bpre[b] + s[t] - v;
    if (idx < N_NODES) { rowptr[idx] = ex; cursor[idx] = ex; }
    if (idx == N_NODES - 1) rowptr[N_NODES] = ex + v;
}

// fill CSR: ssrc[pos]=src (for layer 2) and id16[pos]=x_ids[src] (for layer 1)
__global__ __launch_bounds__(256) void k_fill(const int* __restrict__ src,
                                              const int* __restrict__ dst,
                                              const int* __restrict__ xids,
                                              int* __restrict__ cursor,
                                              int* __restrict__ ssrc,
                                              u16* __restrict__ id16) {
    int e = blockIdx.x * 256 + threadIdx.x;
    if (e >= N_EDGES) return;
    int s = src[e];
    int pos = atomicAdd(&cursor[dst[e]], 1);
    ssrc[pos] = s;
    id16[pos] = (u16)xids[s];
}

// ---- prep: W[k][j] f32 -> wT bf16, j-major rows (256B), XOR-swizzled, in ws ----
__global__ __launch_bounds__(256) void k_prep(const float* __restrict__ w11, const float* __restrict__ w12,
                                              const float* __restrict__ w21, const float* __restrict__ w22,
                                              u16* __restrict__ out) {
    int g = blockIdx.x * 256 + threadIdx.x;            // 4 * 8192 threads
    if (g >= 4 * 8192) return;
    int mat = g >> 13, r = g & 8191;
    int j = r & 127, k0 = (r >> 7) * 2;
    const float* w = (mat == 0) ? w11 : (mat == 1) ? w12 : (mat == 2) ? w21 : w22;
    float v0 = w[k0 * DIM + j];
    float v1 = w[(k0 + 1) * DIM + j];
    u32 p = pack2(v0, v1);
    char* base = (char*)(out + mat * 16384);
    *(u32*)(base + j * 256 + ((2 * k0) ^ ((j & 7) << 4))) = p;
}

// ---- layer-1 aggregate from the 128 KB embbf table; 4-way unrolled, bf16 out ----
__global__ __launch_bounds__(256) void k_agg_emb(const u16* __restrict__ embbf,
                                                 const u16* __restrict__ id16,
                                                 const int* __restrict__ rowptr,
                                                 u16* __restrict__ aggbf) {
    int wave = (blockIdx.x * 256 + threadIdx.x) >> 6;
    if (wave >= N_NODES) return;
    int lane = threadIdx.x & 63;
    int beg = rowptr[wave], end = rowptr[wave + 1];
    float ax0 = 0.f, ay0 = 0.f, ax1 = 0.f, ay1 = 0.f;
    float ax2 = 0.f, ay2 = 0.f, ax3 = 0.f, ay3 = 0.f;
    int i = beg;
    for (; i + 4 <= end; i += 4) {
        int s0 = id16[i], s1 = id16[i + 1], s2 = id16[i + 2], s3 = id16[i + 3];
        u32 v0 = *(const u32*)(embbf + s0 * DIM + lane * 2);
        u32 v1 = *(const u32*)(embbf + s1 * DIM + lane * 2);
        u32 v2 = *(const u32*)(embbf + s2 * DIM + lane * 2);
        u32 v3 = *(const u32*)(embbf + s3 * DIM + lane * 2);
        ax0 += bf2f((u16)v0); ay0 += bf2f((u16)(v0 >> 16));
        ax1 += bf2f((u16)v1); ay1 += bf2f((u16)(v1 >> 16));
        ax2 += bf2f((u16)v2); ay2 += bf2f((u16)(v2 >> 16));
        ax3 += bf2f((u16)v3); ay3 += bf2f((u16)(v3 >> 16));
    }
    for (; i < end; i++) {
        int s = id16[i];
        u32 v = *(const u32*)(embbf + s * DIM + lane * 2);
        ax0 += bf2f((u16)v); ay0 += bf2f((u16)(v >> 16));
    }
    float ax = (ax0 + ax1) + (ax2 + ax3);
    float ay = (ay0 + ay1) + (ay2 + ay3);
    *(u32*)(aggbf + wave * DIM + lane * 2) = pack2(ax, ay);
}

// ---- layer-2 aggregate from h1; 4-way unrolled, bf16 out --------------------
__global__ __launch_bounds__(256) void k_agg_bf16(const u16* __restrict__ x,
                                                  const int* __restrict__ rowptr,
                                                  const int* __restrict__ ssrc,
                                                  u16* __restrict__ aggbf) {
    int wave = (blockIdx.x * 256 + threadIdx.x) >> 6;
    if (wave >= N_NODES) return;
    int lane = threadIdx.x & 63;
    int beg = rowptr[wave], end = rowptr[wave + 1];
    float ax0 = 0.f, ay0 = 0.f, ax1 = 0.f, ay1 = 0.f;
    float ax2 = 0.f, ay2 = 0.f, ax3 = 0.f, ay3 = 0.f;
    int i = beg;
    for (; i + 4 <= end; i += 4) {
        int s0 = ssrc[i], s1 = ssrc[i + 1], s2 = ssrc[i + 2], s3 = ssrc[i + 3];
        u32 v0 = *(const u32*)(x + s0 * DIM + lane * 2);
        u32 v1 = *(const u32*)(x + s1 * DIM + lane * 2);
        u32 v2 = *(const u32*)(x + s2 * DIM + lane * 2);
        u32 v3 = *(const u32*)(x + s3 * DIM + lane * 2);
        ax0 += bf2f((u16)v0); ay0 += bf2f((u16)(v0 >> 16));
        ax1 += bf2f((u16)v1); ay1 += bf2f((u16)(v1 >> 16));
        ax2 += bf2f((u16)v2); ay2 += bf2f((u16)(v2 >> 16));
        ax3 += bf2f((u16)v3); ay3 += bf2f((u16)(v3 >> 16));
    }
    for (; i < end; i++) {
        int s = ssrc[i];
        u32 v = *(const u32*)(x + s * DIM + lane * 2);
        ax0 += bf2f((u16)v); ay0 += bf2f((u16)(v >> 16));
    }
    float ax = (ax0 + ax1) + (ax2 + ax3);
    float ay = (ay0 + ay1) + (ay2 + ay3);
    *(u32*)(aggbf + wave * DIM + lane * 2) = pack2(ax, ay);
}

// ------- fused GIN MLP via MFMA: h = relu( relu(bn((x+agg)@wa+ba)) @ wb + bb ) -------
// GATHER: xin row = embbf[ids[node]] (layer 1), else xin row = xin[node] (layer 2)
template<bool GATHER>
__global__ __launch_bounds__(256) void k_mlp(const u16* __restrict__ xin,
                                             const int* __restrict__ ids,
                                             const u16* __restrict__ aggbf,
                                             const u16* __restrict__ wsa, const float* __restrict__ ba,
                                             const float* __restrict__ gg, const float* __restrict__ be,
                                             const float* __restrict__ mm, const float* __restrict__ vv,
                                             const u16* __restrict__ wsb, const float* __restrict__ bb,
                                             u16* __restrict__ hout, int n) {
    __shared__ u16 w_s[16384];                         // 32 KB
    __shared__ u16 act_s[4096];                        // 8 KB: [32 nodes][128 k] swizzled
    __shared__ u16 mid_s[4096];                        // 8 KB
    __shared__ float pA[DIM], pS[DIM], pH[DIM], pB[DIM];
    int tid = threadIdx.x;
    int base = blockIdx.x * 32;

    {   // stage pre-swizzled wa: plain linear copy
        const uint4* s0 = (const uint4*)wsa;
        uint4* d0 = (uint4*)w_s;
        for (int i = tid; i < 2048; i += 256) d0[i] = s0[i];
    }
    if (tid < DIM) {
        float s = gg[tid] * rsqrtf(vv[tid] + 1e-5f);
        pS[tid] = s; pH[tid] = be[tid] - mm[tid] * s;
        pA[tid] = ba[tid]; pB[tid] = bb[tid];
    }
    // stage activations (x + agg) -> bf16, swizzled rows
    for (int i = tid; i < 2048; i += 256) {
        int node = i >> 6, ku = i & 63;                // ku: u32 index (2 dims)
        int gnode = base + node;
        float v0 = 0.f, v1 = 0.f;
        if (gnode < n) {
            const u16* row = GATHER ? (xin + ids[gnode] * DIM) : (xin + gnode * DIM);
            u32 xv = *(const u32*)(row + ku * 2);
            u32 av = *(const u32*)(aggbf + gnode * DIM + ku * 2);
            v0 = bf2f((u16)xv) + bf2f((u16)av);
            v1 = bf2f((u16)(xv >> 16)) + bf2f((u16)(av >> 16));
        }
        *(u32*)((char*)act_s + node * 256 + ((4 * ku) ^ ((node & 7) << 4))) = pack2(v0, v1);
    }
    __syncthreads();

    int lane = tid & 63;
    int wv = tid >> 6;
    int fr = lane & 15;                                // output col within tile
    int fq = lane >> 4;                                // k-subgroup / row-group
    int ntb = wv * 2;                                  // first N-tile of this wave
    int xorv = (fr & 7) << 4;

    f32x4 acc[2][2];
    // ---- phase 1: (act @ wa) + ba -> BN -> ReLU -> mid ----
#pragma unroll
    for (int nt = 0; nt < 2; nt++) {
        float b = pA[(ntb + nt) * 16 + fr];
        f32x4 bb4 = {b, b, b, b};
        acc[0][nt] = bb4; acc[1][nt] = bb4;
    }
#pragma unroll
    for (int kb = 0; kb < 4; kb++) {
        int koff = (kb * 64 + fq * 16) ^ xorv;
        bf16x8 a0 = *(const bf16x8*)((const char*)act_s + fr * 256 + koff);
        bf16x8 a1 = *(const bf16x8*)((const char*)act_s + (16 + fr) * 256 + koff);
        bf16x8 b0 = *(const bf16x8*)((const char*)w_s + (ntb * 16 + fr) * 256 + koff);
        bf16x8 b1 = *(const bf16x8*)((const char*)w_s + ((ntb + 1) * 16 + fr) * 256 + koff);
        acc[0][0] = MFMA16(a0, b0, acc[0][0]);
        acc[0][1] = MFMA16(a0, b1, acc[0][1]);
        acc[1][0] = MFMA16(a1, b0, acc[1][0]);
        acc[1][1] = MFMA16(a1, b1, acc[1][1]);
    }
#pragma unroll
    for (int nt = 0; nt < 2; nt++) {
        int j = (ntb + nt) * 16 + fr;
        float sc = pS[j], sh = pH[j];
#pragma unroll
        for (int mt = 0; mt < 2; mt++)
#pragma unroll
            for (int r = 0; r < 4; r++) {
                int node = mt * 16 + fq * 4 + r;
                float v = fmaxf(acc[mt][nt][r] * sc + sh, 0.f);
                *(u16*)((char*)mid_s + node * 256 + ((2 * j) ^ ((node & 7) << 4))) = f2bf(v);
            }
    }
    __syncthreads();
    {   // restage with wb
        const uint4* s0 = (const uint4*)wsb;
        uint4* d0 = (uint4*)w_s;
        for (int i = tid; i < 2048; i += 256) d0[i] = s0[i];
    }
    __syncthreads();
    // ---- phase 2: (mid @ wb) + bb -> ReLU -> hout ----
#pragma unroll
    for (int nt = 0; nt < 2; nt++) {
        float b = pB[(ntb + nt) * 16 + fr];
        f32x4 bb4 = {b, b, b, b};
        acc[0][nt] = bb4; acc[1][nt] = bb4;
    }
#pragma unroll
    for (int kb = 0; kb < 4; kb++) {
        int koff = (kb * 64 + fq * 16) ^ xorv;
        bf16x8 a0 = *(const bf16x8*)((const char*)mid_s + fr * 256 + koff);
        bf16x8 a1 = *(const bf16x8*)((const char*)mid_s + (16 + fr) * 256 + koff);
        bf16x8 b0 = *(const bf16x8*)((const char*)w_s + (ntb * 16 + fr) * 256 + koff);
        bf16x8 b1 = *(const bf16x8*)((const char*)w_s + ((ntb + 1) * 16 + fr) * 256 + koff);
        acc[0][0] = MFMA16(a0, b0, acc[0][0]);
        acc[0][1] = MFMA16(a0, b1, acc[0][1]);
        acc[1][0] = MFMA16(a1, b0, acc[1][0]);
        acc[1][1] = MFMA16(a1, b1, acc[1][1]);
    }
#pragma unroll
    for (int nt = 0; nt < 2; nt++) {
        int j = (ntb + nt) * 16 + fr;
#pragma unroll
        for (int mt = 0; mt < 2; mt++)
#pragma unroll
            for (int r = 0; r < 4; r++) {
                int node = base + mt * 16 + fq * 4 + r;
                if (node < n) hout[node * DIM + j] = f2bf(fmaxf(acc[mt][nt][r], 0.f));
            }
    }
}

// ------------- pool: pooled[g][0:128]=sum h1, [128:256]=sum h2 ----------------
__global__ __launch_bounds__(256) void k_pool(const int* __restrict__ batch,
                                              const u16* __restrict__ h1,
                                              const u16* __restrict__ h2,
                                              float* __restrict__ pool) {
    int g = blockIdx.x;
    int tid = threadIdx.x;
    int lo = 0, hi = N_NODES;
    while (lo < hi) { int m = (lo + hi) >> 1; if (batch[m] < g) lo = m + 1; else hi = m; }
    int start = lo;
    hi = N_NODES;
    while (lo < hi) { int m = (lo + hi) >> 1; if (batch[m] < g + 1) lo = m + 1; else hi = m; }
    int end = lo;
    int half = (tid >> 6) & 1;                         // 0: h1, 1: h2
    int ju = tid & 63;                                 // u32 index within 128-dim row
    int par = tid >> 7;                                // node parity
    const u16* h = half ? h2 : h1;
    float a0 = 0.f, a1 = 0.f;
    for (int i = start + par; i < end; i += 2) {
        u32 v = *(const u32*)(h + i * DIM + ju * 2);
        a0 += bf2f((u16)v); a1 += bf2f((u16)(v >> 16));
    }
    __shared__ float2 red[2][128];
    red[par][half * 64 + ju] = make_float2(a0, a1);
    __syncthreads();
    if (tid < 128) {
        float2 r0 = red[0][tid], r1 = red[1][tid];
        pool[g * 256 + tid * 2]     = r0.x + r1.x;
        pool[g * 256 + tid * 2 + 1] = r0.y + r1.y;
    }
}

// ------------- head1: hg = relu(pool @ wl1 + bl1)  [500 x 128] ----------------
__global__ __launch_bounds__(256) void k_head1(const float* __restrict__ pool,
                                               const float* __restrict__ wl1,
                                               const float* __restrict__ bl1,
                                               float* __restrict__ hg) {
    int gid = blockIdx.x * 256 + threadIdx.x;
    if (gid >= N_GR * DIM) return;
    int g = gid >> 7, j = gid & 127;
    float acc = bl1[j];
    const float* p = pool + g * 256;
#pragma unroll 4
    for (int k = 0; k < 256; k++) acc = fmaf(p[k], wl1[k * DIM + j], acc);
    hg[gid] = fmaxf(acc, 0.f);
}

// ------------- head2: out = hg @ wl2 + bl2  [500 x 10], f32 -------------------
__global__ __launch_bounds__(256) void k_head2(const float* __restrict__ hg,
                                               const float* __restrict__ wl2,
                                               const float* __restrict__ bl2,
                                               float* __restrict__ out) {
    int gid = blockIdx.x * 256 + threadIdx.x;
    if (gid >= N_GR * N_OUT) return;
    int g = gid / N_OUT, o = gid - g * N_OUT;
    float acc = bl2[o];
    const float* h = hg + g * DIM;
#pragma unroll 4
    for (int k = 0; k < DIM; k++) acc = fmaf(h[k], wl2[k * N_OUT + o], acc);
    out[gid] = acc;
}

extern "C" void kernel_launch(void* const* d_in, const int* in_sizes, int n_in,
                              void* d_out, int out_size, void* d_ws, size_t ws_size,
                              hipStream_t stream) {
    const int* x_ids = (const int*)d_in[0];
    const int* edges = (const int*)d_in[1];
    const int* batch = (const int*)d_in[2];
    const float* emb = (const float*)d_in[3];
    const float *w11 = (const float*)d_in[4],  *b11 = (const float*)d_in[5];
    const float *g1  = (const float*)d_in[6],  *be1 = (const float*)d_in[7];
    const float *m1  = (const float*)d_in[8],  *v1  = (const float*)d_in[9];
    const float *w12 = (const float*)d_in[10], *b12 = (const float*)d_in[11];
    const float *w21 = (const float*)d_in[12], *b21 = (const float*)d_in[13];
    const float *g2  = (const float*)d_in[14], *be2 = (const float*)d_in[15];
    const float *m2  = (const float*)d_in[16], *v2  = (const float*)d_in[17];
    const float *w22 = (const float*)d_in[18], *b22 = (const float*)d_in[19];
    const float *wl1 = (const float*)d_in[20], *bl1 = (const float*)d_in[21];
    const float *wl2 = (const float*)d_in[22], *bl2 = (const float*)d_in[23];

    const int* src = edges;
    const int* dst = edges + N_EDGES;

    float* out_logits = (float*)d_out;                 // [500*10]
    float* xout = (float*)d_out + N_GR * N_OUT;        // [50000*128]

    char* ws = (char*)d_ws;
    u16*   aggbf  = (u16*)ws;                          // 12,800,000 B (bf16 now)
    u16*   h1     = (u16*)(ws + 25600000);             // 12,800,000 B
    u16*   h2     = (u16*)(ws + 38400000);             // 12,800,000 B
    // embbf/id16 alias the h2 region: both dead before k_mlp<false> writes h2
    u16*   embbf  = (u16*)(ws + 38400000);             //    128,000 B
    u16*   id16   = (u16*)(ws + 38528000);             //  1,600,000 B
    float* pool   = (float*)(ws + 51200000);           //    512,000 B
    int*   bsum   = (int*)(ws + 51200000);             //   (overlaps pool; dead by k_pool)
    int*   bpre   = (int*)(ws + 51204096);
    float* hg     = (float*)(ws + 51712000);           //    256,000 B
    int*   deg    = (int*)(ws + 51968000);             //    200,000 B
    int*   rowptr = (int*)(ws + 52168000);             //    200,016 B
    int*   cursor = (int*)(ws + 52368016);             //    200,000 B (reused for wsz after k_fill)
    u16*   wsz    = (u16*)(ws + 52368016);             //    131,072 B
    int*   ssrc   = (int*)(ws + 52568016);             //  3,200,000 B (ends 55.77 MB)

    u16* wsz1a = wsz;            u16* wsz1b = wsz + 16384;
    u16* wsz2a = wsz + 32768;    u16* wsz2b = wsz + 49152;

    // ---- CSR build (once; shared by both layers) ----
    hipMemsetAsync(deg, 0, (size_t)N_NODES * 4, stream);
    k_hist<<<(N_EDGES + 255) / 256, 256, 0, stream>>>(dst, deg);
    k_scan1<<<196, 256, 0, stream>>>(deg, bsum);
    k_scan2<<<1, 256, 0, stream>>>(bsum, bpre);
    k_scan3<<<196, 256, 0, stream>>>(deg, bpre, rowptr, cursor);
    k_fill<<<(N_EDGES + 255) / 256, 256, 0, stream>>>(src, dst, x_ids, cursor, ssrc, id16);
    // cursor dead; stage swizzled weights + bf16 emb table
    k_prep<<<128, 256, 0, stream>>>(w11, w12, w21, w22, wsz);
    k_embf<<<125, 256, 0, stream>>>(emb, embbf);

    // ---- layer 1 ----
    k_gather<<<(N_NODES * 32) / 256, 256, 0, stream>>>(x_ids, emb, xout);
    k_agg_emb<<<(N_NODES * 64 + 255) / 256, 256, 0, stream>>>(embbf, id16, rowptr, aggbf);
    k_mlp<true><<<(N_NODES + 31) / 32, 256, 0, stream>>>(embbf, x_ids, aggbf, wsz1a, b11, g1, be1, m1, v1, wsz1b, b12, h1, N_NODES);
    // ---- layer 2 ----
    k_agg_bf16<<<(N_NODES * 64 + 255) / 256, 256, 0, stream>>>(h1, rowptr, ssrc, aggbf);
    k_mlp<false><<<(N_NODES + 31) / 32, 256, 0, stream>>>(h1, nullptr, aggbf, wsz2a, b21, g2, be2, m2, v2, wsz2b, b22, h2, N_NODES);
    // ---- readout ----
    k_pool<<<N_GR, 256, 0, stream>>>(batch, h1, h2, pool);
    k_head1<<<(N_GR * DIM + 255) / 256, 256, 0, stream>>>(pool, wl1, bl1, hg);
    k_head2<<<(N_GR * N_OUT + 255) / 256, 256, 0, stream>>>(hg, wl2, bl2, out_logits);
}

// Round 8
// 222.132 us; speedup vs baseline: 20.1680x; 1.2924x over previous
//
#include <hip/hip_runtime.h>
#include <hip/hip_bf16.h>

#define N_NODES 50000
#define N_EDGES 800000
#define DIM 128
#define N_GR 500
#define N_OUT 10

typedef unsigned short u16;
typedef unsigned int u32;
typedef __attribute__((ext_vector_type(8))) short bf16x8;
typedef __attribute__((ext_vector_type(4))) float f32x4;

#define MFMA16(a, b, c) __builtin_amdgcn_mfma_f32_16x16x32_bf16(a, b, c, 0, 0, 0)

__device__ __forceinline__ float bf2f(u16 u) {
    union { u32 i; float f; } c; c.i = ((u32)u) << 16; return c.f;
}
__device__ __forceinline__ u16 f2bf(float f) {
    union { float f; u32 i; } c; c.f = f;
    u32 i = c.i;
    u32 r = i + 0x7FFFu + ((i >> 16) & 1u);
    return (u16)(r >> 16);
}
__device__ __forceinline__ u32 pack2(float a, float b) {
    return (u32)f2bf(a) | ((u32)f2bf(b) << 16);
}

// ---------------- gather: x = emb[x_ids], f32 copy into d_out ----------------
__global__ __launch_bounds__(256) void k_gather(const int* __restrict__ ids,
                                                const float* __restrict__ emb,
                                                float* __restrict__ xout) {
    int gid = blockIdx.x * 256 + threadIdx.x;          // N*32 threads
    if (gid >= N_NODES * 32) return;
    int node = gid >> 5, seg = gid & 31;
    int id = ids[node];
    float4 v = *(const float4*)(emb + id * DIM + seg * 4);
    *(float4*)(xout + node * DIM + seg * 4) = v;
}

// ------- hist: deg count + per-edge rank within its dst bucket (coalesced) ----
__global__ __launch_bounds__(256) void k_hist(const int* __restrict__ dst,
                                              int* __restrict__ deg,
                                              u16* __restrict__ rank16) {
    int e = blockIdx.x * 256 + threadIdx.x;
    if (e >= N_EDGES) return;
    int r = atomicAdd(&deg[dst[e]], 1);
    rank16[e] = (u16)r;
}

__global__ __launch_bounds__(256) void k_scan1(const int* __restrict__ deg, int* __restrict__ bsum) {
    int t = threadIdx.x, b = blockIdx.x;
    int idx = b * 256 + t;
    int v = (idx < N_NODES) ? deg[idx] : 0;
#pragma unroll
    for (int o = 32; o > 0; o >>= 1) v += __shfl_down(v, o, 64);
    __shared__ int wsum[4];
    if ((t & 63) == 0) wsum[t >> 6] = v;
    __syncthreads();
    if (t == 0) bsum[b] = wsum[0] + wsum[1] + wsum[2] + wsum[3];
}

__global__ __launch_bounds__(256) void k_scan2(const int* __restrict__ bsum, int* __restrict__ bpre) {
    __shared__ int s[256];
    int t = threadIdx.x;
    int v = (t < 196) ? bsum[t] : 0;
    s[t] = v; __syncthreads();
    for (int o = 1; o < 256; o <<= 1) {
        int x = (t >= o) ? s[t - o] : 0;
        __syncthreads();
        s[t] += x;
        __syncthreads();
    }
    if (t < 196) bpre[t] = s[t] - v;                   // exclusive prefix
}

__global__ __launch_bounds__(256) void k_scan3(const int* __restrict__ deg,
                                               const int* __restrict__ bpre,
                                               int* __restrict__ rowptr) {
    __shared__ int s[256];
    int t = threadIdx.x, b = blockIdx.x;
    int idx = b * 256 + t;
    int v = (idx < N_NODES) ? deg[idx] : 0;
    s[t] = v; __syncthreads();
    for (int o = 1; o < 256; o <<= 1) {
        int x = (t >= o) ? s[t - o] : 0;
        __syncthreads();
        s[t] += x;
        __syncthreads();
    }
    int ex = bpre[b] + s[t] - v;
    if (idx < N_NODES) rowptr[idx] = ex;
    if (idx == N_NODES - 1) rowptr[N_NODES] = ex + v;
}

// ---- fill (atomic-free): sid[rowptr[dst]+rank] = src | (x_ids[src] << 17) ----
__global__ __launch_bounds__(256) void k_fill(const int* __restrict__ src,
                                              const int* __restrict__ dst,
                                              const int* __restrict__ xids,
                                              const int* __restrict__ rowptr,
                                              const u16* __restrict__ rank16,
                                              u32* __restrict__ sid) {
    int e = blockIdx.x * 256 + threadIdx.x;
    if (e >= N_EDGES) return;
    int s = src[e];
    int pos = rowptr[dst[e]] + rank16[e];
    sid[pos] = (u32)s | ((u32)xids[s] << 17);
}

// ---- prep: 4x weight f32 -> wT bf16 swizzled, plus emb f32 -> bf16 table ----
__global__ __launch_bounds__(256) void k_prep(const float* __restrict__ w11, const float* __restrict__ w12,
                                              const float* __restrict__ w21, const float* __restrict__ w22,
                                              const float* __restrict__ emb,
                                              u16* __restrict__ wout, u16* __restrict__ embbf) {
    int g = blockIdx.x * 256 + threadIdx.x;
    if (g < 4 * 8192) {
        int mat = g >> 13, r = g & 8191;
        int j = r & 127, k0 = (r >> 7) * 2;
        const float* w = (mat == 0) ? w11 : (mat == 1) ? w12 : (mat == 2) ? w21 : w22;
        float v0 = w[k0 * DIM + j];
        float v1 = w[(k0 + 1) * DIM + j];
        char* base = (char*)(wout + mat * 16384);
        *(u32*)(base + j * 256 + ((2 * k0) ^ ((j & 7) << 4))) = pack2(v0, v1);
    } else {
        int i = g - 4 * 8192;                          // 0..31999
        if (i < N_GR * DIM / 2) {
            float2 p = *(const float2*)(emb + i * 2);
            ((u32*)embbf)[i] = pack2(p.x, p.y);
        }
    }
}

// ---- layer-1 aggregate from the 128 KB embbf table; 4-way unrolled, bf16 out ----
__global__ __launch_bounds__(256) void k_agg_emb(const u16* __restrict__ embbf,
                                                 const u32* __restrict__ sid,
                                                 const int* __restrict__ rowptr,
                                                 u16* __restrict__ aggbf) {
    int wave = (blockIdx.x * 256 + threadIdx.x) >> 6;
    if (wave >= N_NODES) return;
    int lane = threadIdx.x & 63;
    int beg = rowptr[wave], end = rowptr[wave + 1];
    float ax0 = 0.f, ay0 = 0.f, ax1 = 0.f, ay1 = 0.f;
    float ax2 = 0.f, ay2 = 0.f, ax3 = 0.f, ay3 = 0.f;
    int i = beg;
    for (; i + 4 <= end; i += 4) {
        int s0 = sid[i] >> 17, s1 = sid[i + 1] >> 17, s2 = sid[i + 2] >> 17, s3 = sid[i + 3] >> 17;
        u32 v0 = *(const u32*)(embbf + s0 * DIM + lane * 2);
        u32 v1 = *(const u32*)(embbf + s1 * DIM + lane * 2);
        u32 v2 = *(const u32*)(embbf + s2 * DIM + lane * 2);
        u32 v3 = *(const u32*)(embbf + s3 * DIM + lane * 2);
        ax0 += bf2f((u16)v0); ay0 += bf2f((u16)(v0 >> 16));
        ax1 += bf2f((u16)v1); ay1 += bf2f((u16)(v1 >> 16));
        ax2 += bf2f((u16)v2); ay2 += bf2f((u16)(v2 >> 16));
        ax3 += bf2f((u16)v3); ay3 += bf2f((u16)(v3 >> 16));
    }
    for (; i < end; i++) {
        int s = sid[i] >> 17;
        u32 v = *(const u32*)(embbf + s * DIM + lane * 2);
        ax0 += bf2f((u16)v); ay0 += bf2f((u16)(v >> 16));
    }
    float ax = (ax0 + ax1) + (ax2 + ax3);
    float ay = (ay0 + ay1) + (ay2 + ay3);
    *(u32*)(aggbf + wave * DIM + lane * 2) = pack2(ax, ay);
}

// ---- layer-2 aggregate from h1; 4-way unrolled, bf16 out --------------------
__global__ __launch_bounds__(256) void k_agg_bf16(const u16* __restrict__ x,
                                                  const int* __restrict__ rowptr,
                                                  const u32* __restrict__ sid,
                                                  u16* __restrict__ aggbf) {
    int wave = (blockIdx.x * 256 + threadIdx.x) >> 6;
    if (wave >= N_NODES) return;
    int lane = threadIdx.x & 63;
    int beg = rowptr[wave], end = rowptr[wave + 1];
    float ax0 = 0.f, ay0 = 0.f, ax1 = 0.f, ay1 = 0.f;
    float ax2 = 0.f, ay2 = 0.f, ax3 = 0.f, ay3 = 0.f;
    int i = beg;
    for (; i + 4 <= end; i += 4) {
        int s0 = sid[i] & 0x1FFFF, s1 = sid[i + 1] & 0x1FFFF;
        int s2 = sid[i + 2] & 0x1FFFF, s3 = sid[i + 3] & 0x1FFFF;
        u32 v0 = *(const u32*)(x + s0 * DIM + lane * 2);
        u32 v1 = *(const u32*)(x + s1 * DIM + lane * 2);
        u32 v2 = *(const u32*)(x + s2 * DIM + lane * 2);
        u32 v3 = *(const u32*)(x + s3 * DIM + lane * 2);
        ax0 += bf2f((u16)v0); ay0 += bf2f((u16)(v0 >> 16));
        ax1 += bf2f((u16)v1); ay1 += bf2f((u16)(v1 >> 16));
        ax2 += bf2f((u16)v2); ay2 += bf2f((u16)(v2 >> 16));
        ax3 += bf2f((u16)v3); ay3 += bf2f((u16)(v3 >> 16));
    }
    for (; i < end; i++) {
        int s = sid[i] & 0x1FFFF;
        u32 v = *(const u32*)(x + s * DIM + lane * 2);
        ax0 += bf2f((u16)v); ay0 += bf2f((u16)(v >> 16));
    }
    float ax = (ax0 + ax1) + (ax2 + ax3);
    float ay = (ay0 + ay1) + (ay2 + ay3);
    *(u32*)(aggbf + wave * DIM + lane * 2) = pack2(ax, ay);
}

// ------- fused GIN MLP via MFMA: h = relu( relu(bn((x+agg)@wa+ba)) @ wb + bb ) -------
template<bool GATHER>
__global__ __launch_bounds__(256) void k_mlp(const u16* __restrict__ xin,
                                             const int* __restrict__ ids,
                                             const u16* __restrict__ aggbf,
                                             const u16* __restrict__ wsa, const float* __restrict__ ba,
                                             const float* __restrict__ gg, const float* __restrict__ be,
                                             const float* __restrict__ mm, const float* __restrict__ vv,
                                             const u16* __restrict__ wsb, const float* __restrict__ bb,
                                             u16* __restrict__ hout, int n) {
    __shared__ u16 w_s[16384];                         // 32 KB
    __shared__ u16 act_s[4096];                        // 8 KB: [32 nodes][128 k] swizzled
    __shared__ u16 mid_s[4096];                        // 8 KB
    __shared__ float pA[DIM], pS[DIM], pH[DIM], pB[DIM];
    int tid = threadIdx.x;
    int base = blockIdx.x * 32;

    {   // stage pre-swizzled wa: plain linear copy
        const uint4* s0 = (const uint4*)wsa;
        uint4* d0 = (uint4*)w_s;
        for (int i = tid; i < 2048; i += 256) d0[i] = s0[i];
    }
    if (tid < DIM) {
        float s = gg[tid] * rsqrtf(vv[tid] + 1e-5f);
        pS[tid] = s; pH[tid] = be[tid] - mm[tid] * s;
        pA[tid] = ba[tid]; pB[tid] = bb[tid];
    }
    // stage activations (x + agg) -> bf16, swizzled rows
    for (int i = tid; i < 2048; i += 256) {
        int node = i >> 6, ku = i & 63;                // ku: u32 index (2 dims)
        int gnode = base + node;
        float v0 = 0.f, v1 = 0.f;
        if (gnode < n) {
            const u16* row = GATHER ? (xin + ids[gnode] * DIM) : (xin + gnode * DIM);
            u32 xv = *(const u32*)(row + ku * 2);
            u32 av = *(const u32*)(aggbf + gnode * DIM + ku * 2);
            v0 = bf2f((u16)xv) + bf2f((u16)av);
            v1 = bf2f((u16)(xv >> 16)) + bf2f((u16)(av >> 16));
        }
        *(u32*)((char*)act_s + node * 256 + ((4 * ku) ^ ((node & 7) << 4))) = pack2(v0, v1);
    }
    __syncthreads();

    int lane = tid & 63;
    int wv = tid >> 6;
    int fr = lane & 15;                                // output col within tile
    int fq = lane >> 4;                                // k-subgroup / row-group
    int ntb = wv * 2;                                  // first N-tile of this wave
    int xorv = (fr & 7) << 4;

    f32x4 acc[2][2];
    // ---- phase 1: (act @ wa) + ba -> BN -> ReLU -> mid ----
#pragma unroll
    for (int nt = 0; nt < 2; nt++) {
        float b = pA[(ntb + nt) * 16 + fr];
        f32x4 bb4 = {b, b, b, b};
        acc[0][nt] = bb4; acc[1][nt] = bb4;
    }
#pragma unroll
    for (int kb = 0; kb < 4; kb++) {
        int koff = (kb * 64 + fq * 16) ^ xorv;
        bf16x8 a0 = *(const bf16x8*)((const char*)act_s + fr * 256 + koff);
        bf16x8 a1 = *(const bf16x8*)((const char*)act_s + (16 + fr) * 256 + koff);
        bf16x8 b0 = *(const bf16x8*)((const char*)w_s + (ntb * 16 + fr) * 256 + koff);
        bf16x8 b1 = *(const bf16x8*)((const char*)w_s + ((ntb + 1) * 16 + fr) * 256 + koff);
        acc[0][0] = MFMA16(a0, b0, acc[0][0]);
        acc[0][1] = MFMA16(a0, b1, acc[0][1]);
        acc[1][0] = MFMA16(a1, b0, acc[1][0]);
        acc[1][1] = MFMA16(a1, b1, acc[1][1]);
    }
#pragma unroll
    for (int nt = 0; nt < 2; nt++) {
        int j = (ntb + nt) * 16 + fr;
        float sc = pS[j], sh = pH[j];
#pragma unroll
        for (int mt = 0; mt < 2; mt++)
#pragma unroll
            for (int r = 0; r < 4; r++) {
                int node = mt * 16 + fq * 4 + r;
                float v = fmaxf(acc[mt][nt][r] * sc + sh, 0.f);
                *(u16*)((char*)mid_s + node * 256 + ((2 * j) ^ ((node & 7) << 4))) = f2bf(v);
            }
    }
    __syncthreads();
    {   // restage with wb
        const uint4* s0 = (const uint4*)wsb;
        uint4* d0 = (uint4*)w_s;
        for (int i = tid; i < 2048; i += 256) d0[i] = s0[i];
    }
    __syncthreads();
    // ---- phase 2: (mid @ wb) + bb -> ReLU -> hout ----
#pragma unroll
    for (int nt = 0; nt < 2; nt++) {
        float b = pB[(ntb + nt) * 16 + fr];
        f32x4 bb4 = {b, b, b, b};
        acc[0][nt] = bb4; acc[1][nt] = bb4;
    }
#pragma unroll
    for (int kb = 0; kb < 4; kb++) {
        int koff = (kb * 64 + fq * 16) ^ xorv;
        bf16x8 a0 = *(const bf16x8*)((const char*)mid_s + fr * 256 + koff);
        bf16x8 a1 = *(const bf16x8*)((const char*)mid_s + (16 + fr) * 256 + koff);
        bf16x8 b0 = *(const bf16x8*)((const char*)w_s + (ntb * 16 + fr) * 256 + koff);
        bf16x8 b1 = *(const bf16x8*)((const char*)w_s + ((ntb + 1) * 16 + fr) * 256 + koff);
        acc[0][0] = MFMA16(a0, b0, acc[0][0]);
        acc[0][1] = MFMA16(a0, b1, acc[0][1]);
        acc[1][0] = MFMA16(a1, b0, acc[1][0]);
        acc[1][1] = MFMA16(a1, b1, acc[1][1]);
    }
#pragma unroll
    for (int nt = 0; nt < 2; nt++) {
        int j = (ntb + nt) * 16 + fr;
#pragma unroll
        for (int mt = 0; mt < 2; mt++)
#pragma unroll
            for (int r = 0; r < 4; r++) {
                int node = base + mt * 16 + fq * 4 + r;
                if (node < n) hout[node * DIM + j] = f2bf(fmaxf(acc[mt][nt][r], 0.f));
            }
    }
}

// ------ fused readout: pool(h1,h2) -> relu(@wl1+bl1) -> @wl2+bl2, 1 block/graph ------
__global__ __launch_bounds__(256) void k_readout(const int* __restrict__ batch,
                                                 const u16* __restrict__ h1,
                                                 const u16* __restrict__ h2,
                                                 const float* __restrict__ wl1,
                                                 const float* __restrict__ bl1,
                                                 const float* __restrict__ wl2,
                                                 const float* __restrict__ bl2,
                                                 float* __restrict__ out) {
    int g = blockIdx.x;
    int tid = threadIdx.x;
    int lo = 0, hi = N_NODES;
    while (lo < hi) { int m = (lo + hi) >> 1; if (batch[m] < g) lo = m + 1; else hi = m; }
    int start = lo;
    hi = N_NODES;
    while (lo < hi) { int m = (lo + hi) >> 1; if (batch[m] < g + 1) lo = m + 1; else hi = m; }
    int end = lo;
    // ---- pool into pl[256]: [0:128]=sum h1 dims, [128:256]=sum h2 dims ----
    int half = (tid >> 6) & 1;
    int ju = tid & 63;
    int par = tid >> 7;
    const u16* h = half ? h2 : h1;
    float a0 = 0.f, a1 = 0.f;
    for (int i = start + par; i < end; i += 2) {
        u32 v = *(const u32*)(h + i * DIM + ju * 2);
        a0 += bf2f((u16)v); a1 += bf2f((u16)(v >> 16));
    }
    __shared__ float2 red[2][128];
    __shared__ float pl[256];
    __shared__ float hgs[DIM];
    red[par][half * 64 + ju] = make_float2(a0, a1);
    __syncthreads();
    if (tid < 128) {
        float2 r0 = red[0][tid], r1 = red[1][tid];
        pl[tid * 2]     = r0.x + r1.x;
        pl[tid * 2 + 1] = r0.y + r1.y;
    }
    __syncthreads();
    // ---- head1: hg = relu(pl @ wl1 + bl1); 2 threads per output j ----
    {
        int j = tid & 127, seg = tid >> 7;
        float acc = 0.f;
        const float* w = wl1 + (seg * 128) * DIM + j;
        const float* p = pl + seg * 128;
#pragma unroll 4
        for (int k = 0; k < 128; k++) acc = fmaf(p[k], w[k * DIM], acc);
        ((float*)red)[tid] = acc;
        __syncthreads();
        if (tid < 128)
            hgs[tid] = fmaxf(((float*)red)[tid] + ((float*)red)[tid + 128] + bl1[tid], 0.f);
    }
    __syncthreads();
    // ---- head2: out = hgs @ wl2 + bl2 ----
    if (tid < N_OUT) {
        float acc = bl2[tid];
#pragma unroll 4
        for (int k = 0; k < DIM; k++) acc = fmaf(hgs[k], wl2[k * N_OUT + tid], acc);
        out[g * N_OUT + tid] = acc;
    }
}

extern "C" void kernel_launch(void* const* d_in, const int* in_sizes, int n_in,
                              void* d_out, int out_size, void* d_ws, size_t ws_size,
                              hipStream_t stream) {
    const int* x_ids = (const int*)d_in[0];
    const int* edges = (const int*)d_in[1];
    const int* batch = (const int*)d_in[2];
    const float* emb = (const float*)d_in[3];
    const float *w11 = (const float*)d_in[4],  *b11 = (const float*)d_in[5];
    const float *g1  = (const float*)d_in[6],  *be1 = (const float*)d_in[7];
    const float *m1  = (const float*)d_in[8],  *v1  = (const float*)d_in[9];
    const float *w12 = (const float*)d_in[10], *b12 = (const float*)d_in[11];
    const float *w21 = (const float*)d_in[12], *b21 = (const float*)d_in[13];
    const float *g2  = (const float*)d_in[14], *be2 = (const float*)d_in[15];
    const float *m2  = (const float*)d_in[16], *v2  = (const float*)d_in[17];
    const float *w22 = (const float*)d_in[18], *b22 = (const float*)d_in[19];
    const float *wl1 = (const float*)d_in[20], *bl1 = (const float*)d_in[21];
    const float *wl2 = (const float*)d_in[22], *bl2 = (const float*)d_in[23];

    const int* src = edges;
    const int* dst = edges + N_EDGES;

    float* out_logits = (float*)d_out;                 // [500*10]
    float* xout = (float*)d_out + N_GR * N_OUT;        // [50000*128]

    char* ws = (char*)d_ws;
    u16*   aggbf  = (u16*)ws;                          // 12,800,000 B
    u16*   h1     = (u16*)(ws + 25600000);             // 12,800,000 B
    u16*   h2     = (u16*)(ws + 38400000);             // 12,800,000 B
    // embbf/rank16 alias the h2 region: both dead before k_mlp<false> writes h2
    u16*   embbf  = (u16*)(ws + 38400000);             //    128,000 B
    u16*   rank16 = (u16*)(ws + 38528000);             //  1,600,000 B
    int*   bsum   = (int*)(ws + 51200000);
    int*   bpre   = (int*)(ws + 51204096);
    int*   deg    = (int*)(ws + 51968000);             //    200,000 B
    int*   rowptr = (int*)(ws + 52168000);             //    200,016 B
    u16*   wsz    = (u16*)(ws + 52368016);             //    131,072 B
    u32*   sid    = (u32*)(ws + 52568016);             //  3,200,000 B (ends 55.77 MB)

    u16* wsz1a = wsz;            u16* wsz1b = wsz + 16384;
    u16* wsz2a = wsz + 32768;    u16* wsz2b = wsz + 49152;

    // ---- CSR build (once; shared by both layers) ----
    hipMemsetAsync(deg, 0, (size_t)N_NODES * 4, stream);
    k_hist<<<(N_EDGES + 255) / 256, 256, 0, stream>>>(dst, deg, rank16);
    k_scan1<<<196, 256, 0, stream>>>(deg, bsum);
    k_scan2<<<1, 256, 0, stream>>>(bsum, bpre);
    k_scan3<<<196, 256, 0, stream>>>(deg, bpre, rowptr);
    k_fill<<<(N_EDGES + 255) / 256, 256, 0, stream>>>(src, dst, x_ids, rowptr, rank16, sid);
    k_prep<<<253, 256, 0, stream>>>(w11, w12, w21, w22, emb, wsz, embbf);

    // ---- layer 1 ----
    k_gather<<<(N_NODES * 32) / 256, 256, 0, stream>>>(x_ids, emb, xout);
    k_agg_emb<<<(N_NODES * 64 + 255) / 256, 256, 0, stream>>>(embbf, sid, rowptr, aggbf);
    k_mlp<true><<<(N_NODES + 31) / 32, 256, 0, stream>>>(embbf, x_ids, aggbf, wsz1a, b11, g1, be1, m1, v1, wsz1b, b12, h1, N_NODES);
    // ---- layer 2 ----
    k_agg_bf16<<<(N_NODES * 64 + 255) / 256, 256, 0, stream>>>(h1, rowptr, sid, aggbf);
    k_mlp<false><<<(N_NODES + 31) / 32, 256, 0, stream>>>(h1, nullptr, aggbf, wsz2a, b21, g2, be2, m2, v2, wsz2b, b22, h2, N_NODES);
    // ---- readout ----
    k_readout<<<N_GR, 256, 0, stream>>>(batch, h1, h2, wl1, bl1, wl2, bl2, out_logits);
}

// Round 9
// 212.639 us; speedup vs baseline: 21.0684x; 1.0446x over previous
//
#include <hip/hip_runtime.h>
#include <hip/hip_bf16.h>

#define N_NODES 50000
#define N_EDGES 800000
#define DIM 128
#define N_GR 500
#define N_OUT 10

typedef unsigned short u16;
typedef unsigned int u32;
typedef __attribute__((ext_vector_type(8))) short bf16x8;
typedef __attribute__((ext_vector_type(4))) float f32x4;

#define MFMA16(a, b, c) __builtin_amdgcn_mfma_f32_16x16x32_bf16(a, b, c, 0, 0, 0)

__device__ __forceinline__ float bf2f(u16 u) {
    union { u32 i; float f; } c; c.i = ((u32)u) << 16; return c.f;
}
__device__ __forceinline__ u16 f2bf(float f) {
    union { float f; u32 i; } c; c.f = f;
    u32 i = c.i;
    u32 r = i + 0x7FFFu + ((i >> 16) & 1u);
    return (u16)(r >> 16);
}
__device__ __forceinline__ u32 pack2(float a, float b) {
    return (u32)f2bf(a) | ((u32)f2bf(b) << 16);
}

// ---------------- zero deg (replaces 45us rocclr fillBuffer) ------------------
__global__ __launch_bounds__(256) void k_zero(int* __restrict__ deg) {
    int i = blockIdx.x * 256 + threadIdx.x;
    if (i < N_NODES) deg[i] = 0;
}

// ---------------- gather: x = emb[x_ids], f32 copy into d_out ----------------
__global__ __launch_bounds__(256) void k_gather(const int* __restrict__ ids,
                                                const float* __restrict__ emb,
                                                float* __restrict__ xout) {
    int gid = blockIdx.x * 256 + threadIdx.x;          // N*32 threads
    if (gid >= N_NODES * 32) return;
    int node = gid >> 5, seg = gid & 31;
    int id = ids[node];
    float4 v = *(const float4*)(emb + id * DIM + seg * 4);
    *(float4*)(xout + node * DIM + seg * 4) = v;
}

// ------- hist: deg count + per-edge rank within its dst bucket (coalesced) ----
__global__ __launch_bounds__(256) void k_hist(const int* __restrict__ dst,
                                              int* __restrict__ deg,
                                              u16* __restrict__ rank16) {
    int e = blockIdx.x * 256 + threadIdx.x;
    if (e >= N_EDGES) return;
    int r = atomicAdd(&deg[dst[e]], 1);
    rank16[e] = (u16)r;
}

__global__ __launch_bounds__(256) void k_scan1(const int* __restrict__ deg, int* __restrict__ bsum) {
    int t = threadIdx.x, b = blockIdx.x;
    int idx = b * 256 + t;
    int v = (idx < N_NODES) ? deg[idx] : 0;
#pragma unroll
    for (int o = 32; o > 0; o >>= 1) v += __shfl_down(v, o, 64);
    __shared__ int wsum[4];
    if ((t & 63) == 0) wsum[t >> 6] = v;
    __syncthreads();
    if (t == 0) bsum[b] = wsum[0] + wsum[1] + wsum[2] + wsum[3];
}

__global__ __launch_bounds__(256) void k_scan2(const int* __restrict__ bsum, int* __restrict__ bpre) {
    __shared__ int s[256];
    int t = threadIdx.x;
    int v = (t < 196) ? bsum[t] : 0;
    s[t] = v; __syncthreads();
    for (int o = 1; o < 256; o <<= 1) {
        int x = (t >= o) ? s[t - o] : 0;
        __syncthreads();
        s[t] += x;
        __syncthreads();
    }
    if (t < 196) bpre[t] = s[t] - v;                   // exclusive prefix
}

__global__ __launch_bounds__(256) void k_scan3(const int* __restrict__ deg,
                                               const int* __restrict__ bpre,
                                               int* __restrict__ rowptr) {
    __shared__ int s[256];
    int t = threadIdx.x, b = blockIdx.x;
    int idx = b * 256 + t;
    int v = (idx < N_NODES) ? deg[idx] : 0;
    s[t] = v; __syncthreads();
    for (int o = 1; o < 256; o <<= 1) {
        int x = (t >= o) ? s[t - o] : 0;
        __syncthreads();
        s[t] += x;
        __syncthreads();
    }
    int ex = bpre[b] + s[t] - v;
    if (idx < N_NODES) rowptr[idx] = ex;
    if (idx == N_NODES - 1) rowptr[N_NODES] = ex + v;
}

// ---- fill (atomic-free): sid[rowptr[dst]+rank] = src | (x_ids[src] << 17) ----
__global__ __launch_bounds__(256) void k_fill(const int* __restrict__ src,
                                              const int* __restrict__ dst,
                                              const int* __restrict__ xids,
                                              const int* __restrict__ rowptr,
                                              const u16* __restrict__ rank16,
                                              u32* __restrict__ sid) {
    int e = blockIdx.x * 256 + threadIdx.x;
    if (e >= N_EDGES) return;
    int s = src[e];
    int pos = rowptr[dst[e]] + rank16[e];
    sid[pos] = (u32)s | ((u32)xids[s] << 17);
}

// ---- prep: 4x weight f32 -> wT bf16 swizzled, plus emb f32 -> bf16 table ----
__global__ __launch_bounds__(256) void k_prep(const float* __restrict__ w11, const float* __restrict__ w12,
                                              const float* __restrict__ w21, const float* __restrict__ w22,
                                              const float* __restrict__ emb,
                                              u16* __restrict__ wout, u16* __restrict__ embbf) {
    int g = blockIdx.x * 256 + threadIdx.x;
    if (g < 4 * 8192) {
        int mat = g >> 13, r = g & 8191;
        int j = r & 127, k0 = (r >> 7) * 2;
        const float* w = (mat == 0) ? w11 : (mat == 1) ? w12 : (mat == 2) ? w21 : w22;
        float v0 = w[k0 * DIM + j];
        float v1 = w[(k0 + 1) * DIM + j];
        char* base = (char*)(wout + mat * 16384);
        *(u32*)(base + j * 256 + ((2 * k0) ^ ((j & 7) << 4))) = pack2(v0, v1);
    } else {
        int i = g - 4 * 8192;                          // 0..31999
        if (i < N_GR * DIM / 2) {
            float2 p = *(const float2*)(emb + i * 2);
            ((u32*)embbf)[i] = pack2(p.x, p.y);
        }
    }
}

// ---- layer-1 aggregate from the 128 KB embbf table; 4-way unrolled, bf16 out ----
__global__ __launch_bounds__(256) void k_agg_emb(const u16* __restrict__ embbf,
                                                 const u32* __restrict__ sid,
                                                 const int* __restrict__ rowptr,
                                                 u16* __restrict__ aggbf) {
    int wave = (blockIdx.x * 256 + threadIdx.x) >> 6;
    if (wave >= N_NODES) return;
    int lane = threadIdx.x & 63;
    int beg = rowptr[wave], end = rowptr[wave + 1];
    float ax0 = 0.f, ay0 = 0.f, ax1 = 0.f, ay1 = 0.f;
    float ax2 = 0.f, ay2 = 0.f, ax3 = 0.f, ay3 = 0.f;
    int i = beg;
    for (; i + 4 <= end; i += 4) {
        int s0 = sid[i] >> 17, s1 = sid[i + 1] >> 17, s2 = sid[i + 2] >> 17, s3 = sid[i + 3] >> 17;
        u32 v0 = *(const u32*)(embbf + s0 * DIM + lane * 2);
        u32 v1 = *(const u32*)(embbf + s1 * DIM + lane * 2);
        u32 v2 = *(const u32*)(embbf + s2 * DIM + lane * 2);
        u32 v3 = *(const u32*)(embbf + s3 * DIM + lane * 2);
        ax0 += bf2f((u16)v0); ay0 += bf2f((u16)(v0 >> 16));
        ax1 += bf2f((u16)v1); ay1 += bf2f((u16)(v1 >> 16));
        ax2 += bf2f((u16)v2); ay2 += bf2f((u16)(v2 >> 16));
        ax3 += bf2f((u16)v3); ay3 += bf2f((u16)(v3 >> 16));
    }
    for (; i < end; i++) {
        int s = sid[i] >> 17;
        u32 v = *(const u32*)(embbf + s * DIM + lane * 2);
        ax0 += bf2f((u16)v); ay0 += bf2f((u16)(v >> 16));
    }
    float ax = (ax0 + ax1) + (ax2 + ax3);
    float ay = (ay0 + ay1) + (ay2 + ay3);
    *(u32*)(aggbf + wave * DIM + lane * 2) = pack2(ax, ay);
}

// ---- layer-2 aggregate from h1; 4-way unrolled, bf16 out --------------------
__global__ __launch_bounds__(256) void k_agg_bf16(const u16* __restrict__ x,
                                                  const int* __restrict__ rowptr,
                                                  const u32* __restrict__ sid,
                                                  u16* __restrict__ aggbf) {
    int wave = (blockIdx.x * 256 + threadIdx.x) >> 6;
    if (wave >= N_NODES) return;
    int lane = threadIdx.x & 63;
    int beg = rowptr[wave], end = rowptr[wave + 1];
    float ax0 = 0.f, ay0 = 0.f, ax1 = 0.f, ay1 = 0.f;
    float ax2 = 0.f, ay2 = 0.f, ax3 = 0.f, ay3 = 0.f;
    int i = beg;
    for (; i + 4 <= end; i += 4) {
        int s0 = sid[i] & 0x1FFFF, s1 = sid[i + 1] & 0x1FFFF;
        int s2 = sid[i + 2] & 0x1FFFF, s3 = sid[i + 3] & 0x1FFFF;
        u32 v0 = *(const u32*)(x + s0 * DIM + lane * 2);
        u32 v1 = *(const u32*)(x + s1 * DIM + lane * 2);
        u32 v2 = *(const u32*)(x + s2 * DIM + lane * 2);
        u32 v3 = *(const u32*)(x + s3 * DIM + lane * 2);
        ax0 += bf2f((u16)v0); ay0 += bf2f((u16)(v0 >> 16));
        ax1 += bf2f((u16)v1); ay1 += bf2f((u16)(v1 >> 16));
        ax2 += bf2f((u16)v2); ay2 += bf2f((u16)(v2 >> 16));
        ax3 += bf2f((u16)v3); ay3 += bf2f((u16)(v3 >> 16));
    }
    for (; i < end; i++) {
        int s = sid[i] & 0x1FFFF;
        u32 v = *(const u32*)(x + s * DIM + lane * 2);
        ax0 += bf2f((u16)v); ay0 += bf2f((u16)(v >> 16));
    }
    float ax = (ax0 + ax1) + (ax2 + ax3);
    float ay = (ay0 + ay1) + (ay2 + ay3);
    *(u32*)(aggbf + wave * DIM + lane * 2) = pack2(ax, ay);
}

// ------- fused GIN MLP via MFMA: h = relu( relu(bn((x+agg)@wa+ba)) @ wb + bb ) -------
template<bool GATHER>
__global__ __launch_bounds__(256) void k_mlp(const u16* __restrict__ xin,
                                             const int* __restrict__ ids,
                                             const u16* __restrict__ aggbf,
                                             const u16* __restrict__ wsa, const float* __restrict__ ba,
                                             const float* __restrict__ gg, const float* __restrict__ be,
                                             const float* __restrict__ mm, const float* __restrict__ vv,
                                             const u16* __restrict__ wsb, const float* __restrict__ bb,
                                             u16* __restrict__ hout, int n) {
    __shared__ u16 w_s[16384];                         // 32 KB
    __shared__ u16 act_s[4096];                        // 8 KB: [32 nodes][128 k] swizzled
    __shared__ u16 mid_s[4096];                        // 8 KB
    __shared__ float pA[DIM], pS[DIM], pH[DIM], pB[DIM];
    int tid = threadIdx.x;
    int base = blockIdx.x * 32;

    {   // stage pre-swizzled wa: plain linear copy
        const uint4* s0 = (const uint4*)wsa;
        uint4* d0 = (uint4*)w_s;
        for (int i = tid; i < 2048; i += 256) d0[i] = s0[i];
    }
    if (tid < DIM) {
        float s = gg[tid] * rsqrtf(vv[tid] + 1e-5f);
        pS[tid] = s; pH[tid] = be[tid] - mm[tid] * s;
        pA[tid] = ba[tid]; pB[tid] = bb[tid];
    }
    // stage activations (x + agg) -> bf16, swizzled rows
    for (int i = tid; i < 2048; i += 256) {
        int node = i >> 6, ku = i & 63;                // ku: u32 index (2 dims)
        int gnode = base + node;
        float v0 = 0.f, v1 = 0.f;
        if (gnode < n) {
            const u16* row = GATHER ? (xin + ids[gnode] * DIM) : (xin + gnode * DIM);
            u32 xv = *(const u32*)(row + ku * 2);
            u32 av = *(const u32*)(aggbf + gnode * DIM + ku * 2);
            v0 = bf2f((u16)xv) + bf2f((u16)av);
            v1 = bf2f((u16)(xv >> 16)) + bf2f((u16)(av >> 16));
        }
        *(u32*)((char*)act_s + node * 256 + ((4 * ku) ^ ((node & 7) << 4))) = pack2(v0, v1);
    }
    __syncthreads();

    int lane = tid & 63;
    int wv = tid >> 6;
    int fr = lane & 15;                                // output col within tile
    int fq = lane >> 4;                                // k-subgroup / row-group
    int ntb = wv * 2;                                  // first N-tile of this wave
    int xorv = (fr & 7) << 4;

    f32x4 acc[2][2];
    // ---- phase 1: (act @ wa) + ba -> BN -> ReLU -> mid ----
#pragma unroll
    for (int nt = 0; nt < 2; nt++) {
        float b = pA[(ntb + nt) * 16 + fr];
        f32x4 bb4 = {b, b, b, b};
        acc[0][nt] = bb4; acc[1][nt] = bb4;
    }
#pragma unroll
    for (int kb = 0; kb < 4; kb++) {
        int koff = (kb * 64 + fq * 16) ^ xorv;
        bf16x8 a0 = *(const bf16x8*)((const char*)act_s + fr * 256 + koff);
        bf16x8 a1 = *(const bf16x8*)((const char*)act_s + (16 + fr) * 256 + koff);
        bf16x8 b0 = *(const bf16x8*)((const char*)w_s + (ntb * 16 + fr) * 256 + koff);
        bf16x8 b1 = *(const bf16x8*)((const char*)w_s + ((ntb + 1) * 16 + fr) * 256 + koff);
        acc[0][0] = MFMA16(a0, b0, acc[0][0]);
        acc[0][1] = MFMA16(a0, b1, acc[0][1]);
        acc[1][0] = MFMA16(a1, b0, acc[1][0]);
        acc[1][1] = MFMA16(a1, b1, acc[1][1]);
    }
#pragma unroll
    for (int nt = 0; nt < 2; nt++) {
        int j = (ntb + nt) * 16 + fr;
        float sc = pS[j], sh = pH[j];
#pragma unroll
        for (int mt = 0; mt < 2; mt++)
#pragma unroll
            for (int r = 0; r < 4; r++) {
                int node = mt * 16 + fq * 4 + r;
                float v = fmaxf(acc[mt][nt][r] * sc + sh, 0.f);
                *(u16*)((char*)mid_s + node * 256 + ((2 * j) ^ ((node & 7) << 4))) = f2bf(v);
            }
    }
    __syncthreads();
    {   // restage with wb
        const uint4* s0 = (const uint4*)wsb;
        uint4* d0 = (uint4*)w_s;
        for (int i = tid; i < 2048; i += 256) d0[i] = s0[i];
    }
    __syncthreads();
    // ---- phase 2: (mid @ wb) + bb -> ReLU -> hout ----
#pragma unroll
    for (int nt = 0; nt < 2; nt++) {
        float b = pB[(ntb + nt) * 16 + fr];
        f32x4 bb4 = {b, b, b, b};
        acc[0][nt] = bb4; acc[1][nt] = bb4;
    }
#pragma unroll
    for (int kb = 0; kb < 4; kb++) {
        int koff = (kb * 64 + fq * 16) ^ xorv;
        bf16x8 a0 = *(const bf16x8*)((const char*)mid_s + fr * 256 + koff);
        bf16x8 a1 = *(const bf16x8*)((const char*)mid_s + (16 + fr) * 256 + koff);
        bf16x8 b0 = *(const bf16x8*)((const char*)w_s + (ntb * 16 + fr) * 256 + koff);
        bf16x8 b1 = *(const bf16x8*)((const char*)w_s + ((ntb + 1) * 16 + fr) * 256 + koff);
        acc[0][0] = MFMA16(a0, b0, acc[0][0]);
        acc[0][1] = MFMA16(a0, b1, acc[0][1]);
        acc[1][0] = MFMA16(a1, b0, acc[1][0]);
        acc[1][1] = MFMA16(a1, b1, acc[1][1]);
    }
#pragma unroll
    for (int nt = 0; nt < 2; nt++) {
        int j = (ntb + nt) * 16 + fr;
#pragma unroll
        for (int mt = 0; mt < 2; mt++)
#pragma unroll
            for (int r = 0; r < 4; r++) {
                int node = base + mt * 16 + fq * 4 + r;
                if (node < n) hout[node * DIM + j] = f2bf(fmaxf(acc[mt][nt][r], 0.f));
            }
    }
}

// ------ fused readout: pool(h1,h2) -> relu(@wl1+bl1) -> @wl2+bl2, 1 block/graph ------
__global__ __launch_bounds__(256) void k_readout(const int* __restrict__ batch,
                                                 const u16* __restrict__ h1,
                                                 const u16* __restrict__ h2,
                                                 const float* __restrict__ wl1,
                                                 const float* __restrict__ bl1,
                                                 const float* __restrict__ wl2,
                                                 const float* __restrict__ bl2,
                                                 float* __restrict__ out) {
    int g = blockIdx.x;
    int tid = threadIdx.x;
    int lo = 0, hi = N_NODES;
    while (lo < hi) { int m = (lo + hi) >> 1; if (batch[m] < g) lo = m + 1; else hi = m; }
    int start = lo;
    hi = N_NODES;
    while (lo < hi) { int m = (lo + hi) >> 1; if (batch[m] < g + 1) lo = m + 1; else hi = m; }
    int end = lo;
    // ---- pool into pl[256]: [0:128]=sum h1 dims, [128:256]=sum h2 dims ----
    // 4-way unrolled: 4 independent row loads in flight per thread
    int half = (tid >> 6) & 1;
    int ju = tid & 63;
    int par = tid >> 7;                                // node parity (2 threads/column)
    const u16* h = half ? h2 : h1;
    float a0 = 0.f, b0 = 0.f, a1 = 0.f, b1 = 0.f;
    float a2 = 0.f, b2 = 0.f, a3 = 0.f, b3 = 0.f;
    int i = start + par;
    for (; i + 6 < end; i += 8) {
        u32 v0 = *(const u32*)(h + (i    ) * DIM + ju * 2);
        u32 v1 = *(const u32*)(h + (i + 2) * DIM + ju * 2);
        u32 v2 = *(const u32*)(h + (i + 4) * DIM + ju * 2);
        u32 v3 = *(const u32*)(h + (i + 6) * DIM + ju * 2);
        a0 += bf2f((u16)v0); b0 += bf2f((u16)(v0 >> 16));
        a1 += bf2f((u16)v1); b1 += bf2f((u16)(v1 >> 16));
        a2 += bf2f((u16)v2); b2 += bf2f((u16)(v2 >> 16));
        a3 += bf2f((u16)v3); b3 += bf2f((u16)(v3 >> 16));
    }
    for (; i < end; i += 2) {
        u32 v = *(const u32*)(h + i * DIM + ju * 2);
        a0 += bf2f((u16)v); b0 += bf2f((u16)(v >> 16));
    }
    float sa = (a0 + a1) + (a2 + a3);
    float sb = (b0 + b1) + (b2 + b3);
    __shared__ float2 red[2][128];
    __shared__ float pl[256];
    __shared__ float hgs[DIM];
    red[par][half * 64 + ju] = make_float2(sa, sb);
    __syncthreads();
    if (tid < 128) {
        float2 r0 = red[0][tid], r1 = red[1][tid];
        pl[tid * 2]     = r0.x + r1.x;
        pl[tid * 2 + 1] = r0.y + r1.y;
    }
    __syncthreads();
    // ---- head1: hg = relu(pl @ wl1 + bl1); 2 threads per output j ----
    {
        int j = tid & 127, seg = tid >> 7;
        float acc = 0.f;
        const float* w = wl1 + (seg * 128) * DIM + j;
        const float* p = pl + seg * 128;
#pragma unroll 4
        for (int k = 0; k < 128; k++) acc = fmaf(p[k], w[k * DIM], acc);
        ((float*)red)[tid] = acc;
        __syncthreads();
        if (tid < 128)
            hgs[tid] = fmaxf(((float*)red)[tid] + ((float*)red)[tid + 128] + bl1[tid], 0.f);
    }
    __syncthreads();
    // ---- head2: out = hgs @ wl2 + bl2 ----
    if (tid < N_OUT) {
        float acc = bl2[tid];
#pragma unroll 4
        for (int k = 0; k < DIM; k++) acc = fmaf(hgs[k], wl2[k * N_OUT + tid], acc);
        out[g * N_OUT + tid] = acc;
    }
}

extern "C" void kernel_launch(void* const* d_in, const int* in_sizes, int n_in,
                              void* d_out, int out_size, void* d_ws, size_t ws_size,
                              hipStream_t stream) {
    const int* x_ids = (const int*)d_in[0];
    const int* edges = (const int*)d_in[1];
    const int* batch = (const int*)d_in[2];
    const float* emb = (const float*)d_in[3];
    const float *w11 = (const float*)d_in[4],  *b11 = (const float*)d_in[5];
    const float *g1  = (const float*)d_in[6],  *be1 = (const float*)d_in[7];
    const float *m1  = (const float*)d_in[8],  *v1  = (const float*)d_in[9];
    const float *w12 = (const float*)d_in[10], *b12 = (const float*)d_in[11];
    const float *w21 = (const float*)d_in[12], *b21 = (const float*)d_in[13];
    const float *g2  = (const float*)d_in[14], *be2 = (const float*)d_in[15];
    const float *m2  = (const float*)d_in[16], *v2  = (const float*)d_in[17];
    const float *w22 = (const float*)d_in[18], *b22 = (const float*)d_in[19];
    const float *wl1 = (const float*)d_in[20], *bl1 = (const float*)d_in[21];
    const float *wl2 = (const float*)d_in[22], *bl2 = (const float*)d_in[23];

    const int* src = edges;
    const int* dst = edges + N_EDGES;

    float* out_logits = (float*)d_out;                 // [500*10]
    float* xout = (float*)d_out + N_GR * N_OUT;        // [50000*128]

    char* ws = (char*)d_ws;
    u16*   aggbf  = (u16*)ws;                          // 12,800,000 B
    u16*   h1     = (u16*)(ws + 25600000);             // 12,800,000 B
    u16*   h2     = (u16*)(ws + 38400000);             // 12,800,000 B
    // embbf/rank16 alias the h2 region: both dead before k_mlp<false> writes h2
    u16*   embbf  = (u16*)(ws + 38400000);             //    128,000 B
    u16*   rank16 = (u16*)(ws + 38528000);             //  1,600,000 B
    int*   bsum   = (int*)(ws + 51200000);
    int*   bpre   = (int*)(ws + 51204096);
    int*   deg    = (int*)(ws + 51968000);             //    200,000 B
    int*   rowptr = (int*)(ws + 52168000);             //    200,016 B
    u16*   wsz    = (u16*)(ws + 52368016);             //    131,072 B
    u32*   sid    = (u32*)(ws + 52568016);             //  3,200,000 B (ends 55.77 MB)

    u16* wsz1a = wsz;            u16* wsz1b = wsz + 16384;
    u16* wsz2a = wsz + 32768;    u16* wsz2b = wsz + 49152;

    // ---- CSR build (once; shared by both layers) ----
    k_zero<<<(N_NODES + 255) / 256, 256, 0, stream>>>(deg);
    k_hist<<<(N_EDGES + 255) / 256, 256, 0, stream>>>(dst, deg, rank16);
    k_scan1<<<196, 256, 0, stream>>>(deg, bsum);
    k_scan2<<<1, 256, 0, stream>>>(bsum, bpre);
    k_scan3<<<196, 256, 0, stream>>>(deg, bpre, rowptr);
    k_fill<<<(N_EDGES + 255) / 256, 256, 0, stream>>>(src, dst, x_ids, rowptr, rank16, sid);
    k_prep<<<253, 256, 0, stream>>>(w11, w12, w21, w22, emb, wsz, embbf);

    // ---- layer 1 ----
    k_gather<<<(N_NODES * 32) / 256, 256, 0, stream>>>(x_ids, emb, xout);
    k_agg_emb<<<(N_NODES * 64 + 255) / 256, 256, 0, stream>>>(embbf, sid, rowptr, aggbf);
    k_mlp<true><<<(N_NODES + 31) / 32, 256, 0, stream>>>(embbf, x_ids, aggbf, wsz1a, b11, g1, be1, m1, v1, wsz1b, b12, h1, N_NODES);
    // ---- layer 2 ----
    k_agg_bf16<<<(N_NODES * 64 + 255) / 256, 256, 0, stream>>>(h1, rowptr, sid, aggbf);
    k_mlp<false><<<(N_NODES + 31) / 32, 256, 0, stream>>>(h1, nullptr, aggbf, wsz2a, b21, g2, be2, m2, v2, wsz2b, b22, h2, N_NODES);
    // ---- readout ----
    k_readout<<<N_GR, 256, 0, stream>>>(batch, h1, h2, wl1, bl1, wl2, bl2, out_logits);
}